// Round 1
// baseline (370.616 us; speedup 1.0000x reference)
//
#include <hip/hip_runtime.h>
#include <hip/hip_bf16.h>

// B=8, S=4096, E=512, QKV=512, H=8, D=64, M=B*S=32768
// Pipeline:
//   cvt:      x fp32 -> bf16 (ws)
//   trans:    Wq,Wk,Wv,Wo fp32 [K][N] -> bf16 [N][K] (ws)
//   gemm_qkv: q,k,v = act(x@W+b), bf16; q,k staged in d_out region, v in ws
//   kv:       kv[bh][m][d], ksum[bh][d] partials per s-chunk (fp32, ws)
//   out1:     out1 = z * (q @ kv^T), bf16 (reuses x's ws region)
//   gemm_out: out = out1 @ Wo + bo, fp32 -> d_out

typedef __bf16 bf16x8 __attribute__((ext_vector_type(8)));
typedef float  f32x4  __attribute__((ext_vector_type(4)));

__device__ __forceinline__ float b2f(unsigned short u) {
    unsigned int x = ((unsigned int)u) << 16;
    return __builtin_bit_cast(float, x);
}
__device__ __forceinline__ unsigned short f2b(float f) {
    unsigned int u = __builtin_bit_cast(unsigned int, f);
    unsigned int r = (u + 0x7FFFu + ((u >> 16) & 1u)) >> 16;
    return (unsigned short)r;
}

// ---------------- convert fp32 -> bf16 (vectorized, 4 elems/thread) ----------
__global__ void cvt_f32_bf16(const float* __restrict__ in,
                             unsigned short* __restrict__ out, int n4) {
    int i = blockIdx.x * blockDim.x + threadIdx.x;
    if (i >= n4) return;
    float4 v = ((const float4*)in)[i];
    ushort4 o;
    o.x = f2b(v.x); o.y = f2b(v.y); o.z = f2b(v.z); o.w = f2b(v.w);
    ((ushort4*)out)[i] = o;
}

// ---------------- transpose W [512][512] fp32 -> Wt [N][K] bf16 --------------
__global__ void transpose_w(const float* __restrict__ w0, const float* __restrict__ w1,
                            const float* __restrict__ w2, const float* __restrict__ w3,
                            unsigned short* __restrict__ wt) {
    const float* src = (blockIdx.z == 0) ? w0 : (blockIdx.z == 1) ? w1
                     : (blockIdx.z == 2) ? w2 : w3;
    unsigned short* dst = wt + (size_t)blockIdx.z * 512 * 512;
    __shared__ float tile[64][65];
    int t = threadIdx.x;
    int rb = blockIdx.y * 64, cb = blockIdx.x * 64;
    #pragma unroll
    for (int i = 0; i < 16; i++) {
        int c = t + i * 256; int r = c >> 6, cc = c & 63;
        tile[r][cc] = src[(rb + r) * 512 + cb + cc];
    }
    __syncthreads();
    #pragma unroll
    for (int i = 0; i < 16; i++) {
        int c = t + i * 256; int r = c >> 6, cc = c & 63;
        // Wt[n][k] = W[k][n]; n = cb+r, k = rb+cc
        dst[(cb + r) * 512 + rb + cc] = f2b(tile[cc][r]);
    }
}

// ---------------- 128x128 bf16 MFMA GEMM core --------------------------------
// A: [M][512] bf16 row-major. Bt: [N][512] bf16 (B pre-transposed).
// C[m][n] = sum_k A[m][k]*Bt[n][k] + bias[n], optional elu+1, out bf16 or fp32.
template <bool ACT, bool OUTBF>
__device__ __forceinline__ void gemm128(const unsigned short* __restrict__ A,
                                        const unsigned short* __restrict__ Bt,
                                        const float* __restrict__ bias,
                                        void* __restrict__ Cout,
                                        int mtile, int ntile) {
    __shared__ __align__(16) unsigned short sA[128 * 72];
    __shared__ __align__(16) unsigned short sB[128 * 72];
    const int tid  = threadIdx.x;
    const int wave = tid >> 6, lane = tid & 63;
    const int wm = wave >> 1, wn = wave & 1;
    const int quad = lane >> 4, l16 = lane & 15;
    const int mbase = mtile * 128, nbase = ntile * 128;

    f32x4 acc[4][4];
    #pragma unroll
    for (int i = 0; i < 4; i++)
        #pragma unroll
        for (int j = 0; j < 4; j++) acc[i][j] = (f32x4){0.f, 0.f, 0.f, 0.f};

    for (int kb = 0; kb < 512; kb += 64) {
        #pragma unroll
        for (int i = 0; i < 4; i++) {
            int c = tid + i * 256;
            int r = c >> 3, cc = (c & 7) * 8;
            *(uint4*)&sA[r * 72 + cc] = *(const uint4*)&A[(size_t)(mbase + r) * 512 + kb + cc];
            *(uint4*)&sB[r * 72 + cc] = *(const uint4*)&Bt[(size_t)(nbase + r) * 512 + kb + cc];
        }
        __syncthreads();
        #pragma unroll
        for (int ko = 0; ko < 64; ko += 32) {
            bf16x8 af[4], bfr[4];
            #pragma unroll
            for (int f = 0; f < 4; f++)
                af[f] = *(const bf16x8*)&sA[(wm * 64 + f * 16 + l16) * 72 + ko + quad * 8];
            #pragma unroll
            for (int f = 0; f < 4; f++)
                bfr[f] = *(const bf16x8*)&sB[(wn * 64 + f * 16 + l16) * 72 + ko + quad * 8];
            #pragma unroll
            for (int i = 0; i < 4; i++)
                #pragma unroll
                for (int j = 0; j < 4; j++)
                    acc[i][j] = __builtin_amdgcn_mfma_f32_16x16x32_bf16(af[i], bfr[j], acc[i][j], 0, 0, 0);
        }
        __syncthreads();
    }
    // epilogue: C/D layout col=lane&15, row=quad*4+reg (m89-verified)
    #pragma unroll
    for (int i = 0; i < 4; i++) {
        #pragma unroll
        for (int j = 0; j < 4; j++) {
            int gcol = nbase + wn * 64 + j * 16 + l16;
            float bv = bias[gcol];
            #pragma unroll
            for (int r = 0; r < 4; r++) {
                int grow = mbase + wm * 64 + i * 16 + quad * 4 + r;
                float v = acc[i][j][r] + bv;
                if (ACT) v = v > 0.f ? v + 1.f : __expf(v);
                if (OUTBF) ((unsigned short*)Cout)[(size_t)grow * 512 + gcol] = f2b(v);
                else       ((float*)Cout)[(size_t)grow * 512 + gcol] = v;
            }
        }
    }
}

__global__ __launch_bounds__(256) void gemm_qkv_kernel(
        const unsigned short* __restrict__ xb, const unsigned short* __restrict__ wt,
        const float* __restrict__ bq, const float* __restrict__ bk, const float* __restrict__ bv,
        unsigned short* __restrict__ qb, unsigned short* __restrict__ kb,
        unsigned short* __restrict__ vb) {
    int tensor = blockIdx.y >> 2, ntile = blockIdx.y & 3;
    const unsigned short* Bt = wt + (size_t)tensor * 512 * 512;
    const float* bias = tensor == 0 ? bq : tensor == 1 ? bk : bv;
    unsigned short* out = tensor == 0 ? qb : tensor == 1 ? kb : vb;
    if (tensor < 2) gemm128<true,  true>(xb, Bt, bias, out, blockIdx.x, ntile);
    else            gemm128<false, true>(xb, Bt, bias, out, blockIdx.x, ntile);
}

__global__ __launch_bounds__(256) void gemm_out_kernel(
        const unsigned short* __restrict__ o1b, const unsigned short* __restrict__ wto,
        const float* __restrict__ bo, float* __restrict__ out) {
    gemm128<false, false>(o1b, wto, bo, out, blockIdx.x, blockIdx.y);
}

// ---------------- kv + ksum partials ----------------------------------------
// grid: x = bh (64), y = sc (8).  Each block: 512 s-rows, 8x8 cells/thread,
// 4 waves split s; LDS wave-reduction; one partial buffer write, no atomics.
__global__ __launch_bounds__(256) void kv_kernel(
        const unsigned short* __restrict__ kb, const unsigned short* __restrict__ vb,
        float* __restrict__ kvp, float* __restrict__ ksp) {
    int bh = blockIdx.x, sc = blockIdx.y;
    int b = bh >> 3, h = bh & 7;
    const int tid = threadIdx.x;
    int wave = tid >> 6;
    int cell = tid & 63;
    int m0 = (cell >> 3) * 8, d0 = (cell & 7) * 8;
    __shared__ __align__(16) unsigned short sK[32 * 64];
    __shared__ __align__(16) unsigned short sV[32 * 64];
    __shared__ float sAcc[4096];
    __shared__ float sKs[64];
    float acc[8][8];
    #pragma unroll
    for (int i = 0; i < 8; i++)
        #pragma unroll
        for (int j = 0; j < 8; j++) acc[i][j] = 0.f;
    float ks = 0.f;
    size_t gbase = ((size_t)(b * 4096 + sc * 512)) * 512 + h * 64;

    for (int tile = 0; tile < 16; tile++) {
        {
            int r = tid >> 3, cc = (tid & 7) * 8;
            size_t g = gbase + (size_t)(tile * 32 + r) * 512 + cc;
            *(uint4*)&sK[r * 64 + cc] = *(const uint4*)&kb[g];
            *(uint4*)&sV[r * 64 + cc] = *(const uint4*)&vb[g];
        }
        __syncthreads();
        #pragma unroll
        for (int ss = 0; ss < 8; ss++) {
            int s = wave * 8 + ss;
            uint4 kr = *(const uint4*)&sK[s * 64 + d0];
            uint4 vr = *(const uint4*)&sV[s * 64 + m0];
            float kvals[8], vvals[8];
            const unsigned int* kp = (const unsigned int*)&kr;
            const unsigned int* vp = (const unsigned int*)&vr;
            #pragma unroll
            for (int i = 0; i < 4; i++) {
                kvals[2*i]   = __builtin_bit_cast(float, kp[i] << 16);
                kvals[2*i+1] = __builtin_bit_cast(float, kp[i] & 0xFFFF0000u);
                vvals[2*i]   = __builtin_bit_cast(float, vp[i] << 16);
                vvals[2*i+1] = __builtin_bit_cast(float, vp[i] & 0xFFFF0000u);
            }
            #pragma unroll
            for (int i = 0; i < 8; i++)
                #pragma unroll
                for (int j = 0; j < 8; j++)
                    acc[i][j] += vvals[i] * kvals[j];
            ks += b2f(sK[s * 64 + cell]);
        }
        __syncthreads();
    }
    // reduce 4 waves in LDS
    for (int w = 0; w < 4; w++) {
        if (wave == w) {
            #pragma unroll
            for (int i = 0; i < 8; i++)
                #pragma unroll
                for (int j = 0; j < 8; j++) {
                    int idx = (m0 + i) * 64 + d0 + j;
                    if (w == 0) sAcc[idx] = acc[i][j];
                    else        sAcc[idx] += acc[i][j];
                }
            if (w == 0) sKs[cell] = ks;
            else        sKs[cell] += ks;
        }
        __syncthreads();
    }
    float* kvout = kvp + ((size_t)sc * 64 + bh) * 4096;
    #pragma unroll
    for (int i = 0; i < 16; i++) {
        int idx = tid + i * 256;
        kvout[idx] = sAcc[idx];
    }
    if (tid < 64) ksp[((size_t)sc * 64 + bh) * 64 + tid] = sKs[tid];
}

// ---------------- out1 = z * (q @ kv^T) -------------------------------------
// grid: x = lchunk (16, 256 rows each), y = bh (64). 4 waves x 64 rows.
__global__ __launch_bounds__(256) void out1_kernel(
        const unsigned short* __restrict__ qb,
        const float* __restrict__ kvp, const float* __restrict__ ksp,
        unsigned short* __restrict__ o1) {
    int bh = blockIdx.y, b = bh >> 3, h = bh & 7;
    int lbase = blockIdx.x * 256;
    int tid = threadIdx.x, wave = tid >> 6, lane = tid & 63;
    int quad = lane >> 4, l16 = lane & 15;
    __shared__ __align__(16) unsigned short sKV[64 * 72];
    __shared__ __align__(16) unsigned short sQ[4][64 * 72];
    __shared__ float sKsum[64];
    __shared__ float sZ[256];

    // stage kv: sum 8 s-chunk partials, convert bf16; layout [m][d] == Bt[n][k]
    #pragma unroll
    for (int i = 0; i < 16; i++) {
        int idx = tid + i * 256;
        float s = 0.f;
        #pragma unroll
        for (int sc = 0; sc < 8; sc++) s += kvp[((size_t)sc * 64 + bh) * 4096 + idx];
        sKV[(idx >> 6) * 72 + (idx & 63)] = f2b(s);
    }
    if (tid < 64) {
        float s = 0.f;
        #pragma unroll
        for (int sc = 0; sc < 8; sc++) s += ksp[((size_t)sc * 64 + bh) * 64 + tid];
        sKsum[tid] = s;
    }
    // stage q rows for this wave
    {
        size_t qbase = ((size_t)(b * 4096 + lbase + wave * 64)) * 512 + h * 64;
        #pragma unroll
        for (int i = 0; i < 8; i++) {
            int c = lane + i * 64;
            int r = c >> 3, cc = (c & 7) * 8;
            *(uint4*)&sQ[wave][r * 72 + cc] = *(const uint4*)&qb[qbase + (size_t)r * 512 + cc];
        }
    }
    __syncthreads();
    // z per row: lane handles row=lane of its wave
    {
        float denom = 0.f;
        #pragma unroll
        for (int d = 0; d < 64; d++) denom += b2f(sQ[wave][lane * 72 + d]) * sKsum[d];
        sZ[wave * 64 + lane] = 1.f / (denom + 1e-6f);
    }
    __syncthreads();

    f32x4 acc[4][4];
    #pragma unroll
    for (int i = 0; i < 4; i++)
        #pragma unroll
        for (int j = 0; j < 4; j++) acc[i][j] = (f32x4){0.f, 0.f, 0.f, 0.f};
    #pragma unroll
    for (int ko = 0; ko < 64; ko += 32) {
        bf16x8 af[4], bfr[4];
        #pragma unroll
        for (int f = 0; f < 4; f++)
            af[f] = *(const bf16x8*)&sQ[wave][(f * 16 + l16) * 72 + ko + quad * 8];
        #pragma unroll
        for (int f = 0; f < 4; f++)
            bfr[f] = *(const bf16x8*)&sKV[(f * 16 + l16) * 72 + ko + quad * 8];
        #pragma unroll
        for (int i = 0; i < 4; i++)
            #pragma unroll
            for (int j = 0; j < 4; j++)
                acc[i][j] = __builtin_amdgcn_mfma_f32_16x16x32_bf16(af[i], bfr[j], acc[i][j], 0, 0, 0);
    }
    size_t obase = (size_t)(b * 4096 + lbase + wave * 64);
    #pragma unroll
    for (int i = 0; i < 4; i++)
        #pragma unroll
        for (int j = 0; j < 4; j++)
            #pragma unroll
            for (int r = 0; r < 4; r++) {
                int row = i * 16 + quad * 4 + r;
                float v = acc[i][j][r] * sZ[wave * 64 + row];
                o1[(obase + row) * 512 + h * 64 + j * 16 + l16] = f2b(v);
            }
}

// ---------------- launch -----------------------------------------------------
extern "C" void kernel_launch(void* const* d_in, const int* in_sizes, int n_in,
                              void* d_out, int out_size, void* d_ws, size_t ws_size,
                              hipStream_t stream) {
    const float* x  = (const float*)d_in[0];
    const float* Wq = (const float*)d_in[1];
    const float* bq = (const float*)d_in[2];
    const float* Wk = (const float*)d_in[3];
    const float* bk = (const float*)d_in[4];
    const float* Wv = (const float*)d_in[5];
    const float* bv = (const float*)d_in[6];
    const float* Wo = (const float*)d_in[7];
    const float* bo = (const float*)d_in[8];
    float* out = (float*)d_out;

    char* ws = (char*)d_ws;
    unsigned short* xb  = (unsigned short*)(ws);                  // 32 MB, reused as o1b
    unsigned short* vb  = (unsigned short*)(ws + 33554432ull);    // 32 MB
    unsigned short* wt  = (unsigned short*)(ws + 67108864ull);    // 2 MB: Wq,Wk,Wv,Wo transposed
    float*          kvp = (float*)(ws + 69206016ull);             // 8 MB partials
    float*          ksp = (float*)(ws + 77594624ull);             // 128 KB partials
    // d_out (64 MB fp32) doubles as scratch for q,k (dead before final GEMM)
    unsigned short* qb  = (unsigned short*)d_out;                 // 32 MB
    unsigned short* kb  = (unsigned short*)((char*)d_out + 33554432ull);
    unsigned short* o1b = xb;

    cvt_f32_bf16<<<16384, 256, 0, stream>>>(x, xb, 4194304);
    transpose_w<<<dim3(8, 8, 4), 256, 0, stream>>>(Wq, Wk, Wv, Wo, wt);
    gemm_qkv_kernel<<<dim3(256, 12), 256, 0, stream>>>(xb, wt, bq, bk, bv, qb, kb, vb);
    kv_kernel<<<dim3(64, 8), 256, 0, stream>>>(kb, vb, kvp, ksp);
    out1_kernel<<<dim3(16, 64), 256, 0, stream>>>(qb, kvp, ksp, o1b);
    gemm_out_kernel<<<dim3(256, 4), 256, 0, stream>>>(o1b, wt + 3ull * 512 * 512, bo, out);
}

// Round 2
// 339.675 us; speedup vs baseline: 1.0911x; 1.0911x over previous
//
#include <hip/hip_runtime.h>
#include <hip/hip_bf16.h>

// B=8, S=4096, E=512, QKV=512, H=8, D=64, M=B*S=32768
// Pipeline:
//   cvt:      x fp32 -> bf16 (ws)
//   trans:    Wq,Wk,Wv,Wo fp32 [K][N] -> bf16 [N][K] (ws)
//   gemm_qkv: q,k,v = act(x@W+b), bf16; q,k staged in d_out region, v in ws
//   kv:       kv[bh][m][d], ksum[bh][d] partials per s-chunk (fp32, ws)
//   out1:     out1 = z * (q @ kv^T), bf16 (reuses x's ws region)
//   gemm_out: out = out1 @ Wo + bo, fp32 -> d_out
//
// R2: GEMM core rebuilt on the m97 structure: global_load_lds width=16 async
// staging, unpadded 128x64 LDS tiles (32KB/block -> 4 blocks/CU), XOR swizzle
// of 16B column groups (phys = logical ^ (row&7)) done by permuting each
// lane's GLOBAL source address (lane-constant coff), un-XOR'd at ds_read time.

typedef __bf16 bf16x8 __attribute__((ext_vector_type(8)));
typedef float  f32x4  __attribute__((ext_vector_type(4)));

__device__ __forceinline__ float b2f(unsigned short u) {
    unsigned int x = ((unsigned int)u) << 16;
    return __builtin_bit_cast(float, x);
}
__device__ __forceinline__ unsigned short f2b(float f) {
    unsigned int u = __builtin_bit_cast(unsigned int, f);
    unsigned int r = (u + 0x7FFFu + ((u >> 16) & 1u)) >> 16;
    return (unsigned short)r;
}

__device__ __forceinline__ void load_lds16(const unsigned short* g, unsigned short* l) {
    __builtin_amdgcn_global_load_lds(
        (const __attribute__((address_space(1))) void*)g,
        (__attribute__((address_space(3))) void*)l, 16, 0, 0);
}

// ---------------- convert fp32 -> bf16 (vectorized, 4 elems/thread) ----------
__global__ void cvt_f32_bf16(const float* __restrict__ in,
                             unsigned short* __restrict__ out, int n4) {
    int i = blockIdx.x * blockDim.x + threadIdx.x;
    if (i >= n4) return;
    float4 v = ((const float4*)in)[i];
    ushort4 o;
    o.x = f2b(v.x); o.y = f2b(v.y); o.z = f2b(v.z); o.w = f2b(v.w);
    ((ushort4*)out)[i] = o;
}

// ---------------- transpose W [512][512] fp32 -> Wt [N][K] bf16 --------------
__global__ void transpose_w(const float* __restrict__ w0, const float* __restrict__ w1,
                            const float* __restrict__ w2, const float* __restrict__ w3,
                            unsigned short* __restrict__ wt) {
    const float* src = (blockIdx.z == 0) ? w0 : (blockIdx.z == 1) ? w1
                     : (blockIdx.z == 2) ? w2 : w3;
    unsigned short* dst = wt + (size_t)blockIdx.z * 512 * 512;
    __shared__ float tile[64][65];
    int t = threadIdx.x;
    int rb = blockIdx.y * 64, cb = blockIdx.x * 64;
    #pragma unroll
    for (int i = 0; i < 16; i++) {
        int c = t + i * 256; int r = c >> 6, cc = c & 63;
        tile[r][cc] = src[(rb + r) * 512 + cb + cc];
    }
    __syncthreads();
    #pragma unroll
    for (int i = 0; i < 16; i++) {
        int c = t + i * 256; int r = c >> 6, cc = c & 63;
        // Wt[n][k] = W[k][n]; n = cb+r, k = rb+cc
        dst[(cb + r) * 512 + rb + cc] = f2b(tile[cc][r]);
    }
}

// ---------------- 128x128 bf16 MFMA GEMM core (m97-style) --------------------
// A: [M][512] bf16 row-major. Bt: [N][512] bf16 (B pre-transposed).
// C[m][n] = sum_k A[m][k]*Bt[n][k] + bias[n], optional elu+1, out bf16 or fp32.
// LDS tiles 128x64 bf16 unpadded; 16B groups XOR-swizzled: LDS phys group p at
// row r holds logical group p^(r&7). Staged via global_load_lds (wave-uniform
// LDS base + lane*16), so the swizzle lives in each lane's global address.
template <bool ACT, bool OUTBF>
__device__ __forceinline__ void gemm128(const unsigned short* __restrict__ A,
                                        const unsigned short* __restrict__ Bt,
                                        const float* __restrict__ bias,
                                        void* __restrict__ Cout,
                                        int mtile, int ntile) {
    __shared__ __align__(16) unsigned short sA[128 * 64];
    __shared__ __align__(16) unsigned short sB[128 * 64];
    const int tid  = threadIdx.x;
    const int wave = tid >> 6, lane = tid & 63;
    const int wm = wave >> 1, wn = wave & 1;
    const int quad = lane >> 4, l16 = lane & 15;
    const int mbase = mtile * 128, nbase = ntile * 128;
    // staging lane constants: lane covers (row r0+rsub, phys group lane&7),
    // which must hold logical col group (lane&7)^(rsub) since (r&7)==rsub.
    const int rsub = lane >> 3;
    const int coff = (((lane & 7) ^ rsub) << 3);   // element offset within row

    f32x4 acc[4][4];
    #pragma unroll
    for (int i = 0; i < 4; i++)
        #pragma unroll
        for (int j = 0; j < 4; j++) acc[i][j] = (f32x4){0.f, 0.f, 0.f, 0.f};

    for (int kb = 0; kb < 512; kb += 64) {
        #pragma unroll
        for (int t = 0; t < 4; t++) {
            int r0 = t * 32 + wave * 8;            // wave-uniform row base
            load_lds16(&A[(size_t)(mbase + r0 + rsub) * 512 + kb + coff], &sA[r0 * 64]);
            load_lds16(&Bt[(size_t)(nbase + r0 + rsub) * 512 + kb + coff], &sB[r0 * 64]);
        }
        __syncthreads();
        #pragma unroll
        for (int ko = 0; ko < 64; ko += 32) {
            bf16x8 af[4], bfr[4];
            int pg = ((quad + (ko >> 3)) ^ (l16 & 7)) << 3;  // phys group offset (elems)
            #pragma unroll
            for (int f = 0; f < 4; f++)
                af[f] = *(const bf16x8*)&sA[(wm * 64 + f * 16 + l16) * 64 + pg];
            #pragma unroll
            for (int f = 0; f < 4; f++)
                bfr[f] = *(const bf16x8*)&sB[(wn * 64 + f * 16 + l16) * 64 + pg];
            #pragma unroll
            for (int i = 0; i < 4; i++)
                #pragma unroll
                for (int j = 0; j < 4; j++)
                    acc[i][j] = __builtin_amdgcn_mfma_f32_16x16x32_bf16(af[i], bfr[j], acc[i][j], 0, 0, 0);
        }
        __syncthreads();
    }
    // epilogue: C/D layout col=lane&15, row=quad*4+reg (m89-verified)
    #pragma unroll
    for (int i = 0; i < 4; i++) {
        #pragma unroll
        for (int j = 0; j < 4; j++) {
            int gcol = nbase + wn * 64 + j * 16 + l16;
            float bv = bias[gcol];
            #pragma unroll
            for (int r = 0; r < 4; r++) {
                int grow = mbase + wm * 64 + i * 16 + quad * 4 + r;
                float v = acc[i][j][r] + bv;
                if (ACT) v = v > 0.f ? v + 1.f : __expf(v);
                if (OUTBF) ((unsigned short*)Cout)[(size_t)grow * 512 + gcol] = f2b(v);
                else       ((float*)Cout)[(size_t)grow * 512 + gcol] = v;
            }
        }
    }
}

__global__ __launch_bounds__(256, 4) void gemm_qkv_kernel(
        const unsigned short* __restrict__ xb, const unsigned short* __restrict__ wt,
        const float* __restrict__ bq, const float* __restrict__ bk, const float* __restrict__ bv,
        unsigned short* __restrict__ qb, unsigned short* __restrict__ kb,
        unsigned short* __restrict__ vb) {
    int tensor = blockIdx.y >> 2, ntile = blockIdx.y & 3;
    const unsigned short* Bt = wt + (size_t)tensor * 512 * 512;
    const float* bias = tensor == 0 ? bq : tensor == 1 ? bk : bv;
    unsigned short* out = tensor == 0 ? qb : tensor == 1 ? kb : vb;
    if (tensor < 2) gemm128<true,  true>(xb, Bt, bias, out, blockIdx.x, ntile);
    else            gemm128<false, true>(xb, Bt, bias, out, blockIdx.x, ntile);
}

__global__ __launch_bounds__(256, 4) void gemm_out_kernel(
        const unsigned short* __restrict__ o1b, const unsigned short* __restrict__ wto,
        const float* __restrict__ bo, float* __restrict__ out) {
    gemm128<false, false>(o1b, wto, bo, out, blockIdx.x, blockIdx.y);
}

// ---------------- kv + ksum partials ----------------------------------------
// grid: x = bh (64), y = sc (8).  Each block: 512 s-rows, 8x8 cells/thread,
// 4 waves split s; LDS wave-reduction; one partial buffer write, no atomics.
__global__ __launch_bounds__(256) void kv_kernel(
        const unsigned short* __restrict__ kb, const unsigned short* __restrict__ vb,
        float* __restrict__ kvp, float* __restrict__ ksp) {
    int bh = blockIdx.x, sc = blockIdx.y;
    int b = bh >> 3, h = bh & 7;
    const int tid = threadIdx.x;
    int wave = tid >> 6;
    int cell = tid & 63;
    int m0 = (cell >> 3) * 8, d0 = (cell & 7) * 8;
    __shared__ __align__(16) unsigned short sK[32 * 64];
    __shared__ __align__(16) unsigned short sV[32 * 64];
    __shared__ float sAcc[4096];
    __shared__ float sKs[64];
    float acc[8][8];
    #pragma unroll
    for (int i = 0; i < 8; i++)
        #pragma unroll
        for (int j = 0; j < 8; j++) acc[i][j] = 0.f;
    float ks = 0.f;
    size_t gbase = ((size_t)(b * 4096 + sc * 512)) * 512 + h * 64;

    for (int tile = 0; tile < 16; tile++) {
        {
            int r = tid >> 3, cc = (tid & 7) * 8;
            size_t g = gbase + (size_t)(tile * 32 + r) * 512 + cc;
            *(uint4*)&sK[r * 64 + cc] = *(const uint4*)&kb[g];
            *(uint4*)&sV[r * 64 + cc] = *(const uint4*)&vb[g];
        }
        __syncthreads();
        #pragma unroll
        for (int ss = 0; ss < 8; ss++) {
            int s = wave * 8 + ss;
            uint4 kr = *(const uint4*)&sK[s * 64 + d0];
            uint4 vr = *(const uint4*)&sV[s * 64 + m0];
            float kvals[8], vvals[8];
            const unsigned int* kp = (const unsigned int*)&kr;
            const unsigned int* vp = (const unsigned int*)&vr;
            #pragma unroll
            for (int i = 0; i < 4; i++) {
                kvals[2*i]   = __builtin_bit_cast(float, kp[i] << 16);
                kvals[2*i+1] = __builtin_bit_cast(float, kp[i] & 0xFFFF0000u);
                vvals[2*i]   = __builtin_bit_cast(float, vp[i] << 16);
                vvals[2*i+1] = __builtin_bit_cast(float, vp[i] & 0xFFFF0000u);
            }
            #pragma unroll
            for (int i = 0; i < 8; i++)
                #pragma unroll
                for (int j = 0; j < 8; j++)
                    acc[i][j] += vvals[i] * kvals[j];
            ks += b2f(sK[s * 64 + cell]);
        }
        __syncthreads();
    }
    // reduce 4 waves in LDS
    for (int w = 0; w < 4; w++) {
        if (wave == w) {
            #pragma unroll
            for (int i = 0; i < 8; i++)
                #pragma unroll
                for (int j = 0; j < 8; j++) {
                    int idx = (m0 + i) * 64 + d0 + j;
                    if (w == 0) sAcc[idx] = acc[i][j];
                    else        sAcc[idx] += acc[i][j];
                }
            if (w == 0) sKs[cell] = ks;
            else        sKs[cell] += ks;
        }
        __syncthreads();
    }
    float* kvout = kvp + ((size_t)sc * 64 + bh) * 4096;
    #pragma unroll
    for (int i = 0; i < 16; i++) {
        int idx = tid + i * 256;
        kvout[idx] = sAcc[idx];
    }
    if (tid < 64) ksp[((size_t)sc * 64 + bh) * 64 + tid] = sKs[tid];
}

// ---------------- out1 = z * (q @ kv^T) -------------------------------------
// grid: x = lchunk (16, 256 rows each), y = bh (64). 4 waves x 64 rows.
__global__ __launch_bounds__(256) void out1_kernel(
        const unsigned short* __restrict__ qb,
        const float* __restrict__ kvp, const float* __restrict__ ksp,
        unsigned short* __restrict__ o1) {
    int bh = blockIdx.y, b = bh >> 3, h = bh & 7;
    int lbase = blockIdx.x * 256;
    int tid = threadIdx.x, wave = tid >> 6, lane = tid & 63;
    int quad = lane >> 4, l16 = lane & 15;
    __shared__ __align__(16) unsigned short sKV[64 * 72];
    __shared__ __align__(16) unsigned short sQ[4][64 * 72];
    __shared__ float sKsum[64];
    __shared__ float sZ[256];

    // stage kv: sum 8 s-chunk partials, convert bf16; layout [m][d] == Bt[n][k]
    #pragma unroll
    for (int i = 0; i < 16; i++) {
        int idx = tid + i * 256;
        float s = 0.f;
        #pragma unroll
        for (int sc = 0; sc < 8; sc++) s += kvp[((size_t)sc * 64 + bh) * 4096 + idx];
        sKV[(idx >> 6) * 72 + (idx & 63)] = f2b(s);
    }
    if (tid < 64) {
        float s = 0.f;
        #pragma unroll
        for (int sc = 0; sc < 8; sc++) s += ksp[((size_t)sc * 64 + bh) * 64 + tid];
        sKsum[tid] = s;
    }
    // stage q rows for this wave
    {
        size_t qbase = ((size_t)(b * 4096 + lbase + wave * 64)) * 512 + h * 64;
        #pragma unroll
        for (int i = 0; i < 8; i++) {
            int c = lane + i * 64;
            int r = c >> 3, cc = (c & 7) * 8;
            *(uint4*)&sQ[wave][r * 72 + cc] = *(const uint4*)&qb[qbase + (size_t)r * 512 + cc];
        }
    }
    __syncthreads();
    // z per row: lane handles row=lane of its wave
    {
        float denom = 0.f;
        #pragma unroll
        for (int d = 0; d < 64; d++) denom += b2f(sQ[wave][lane * 72 + d]) * sKsum[d];
        sZ[wave * 64 + lane] = 1.f / (denom + 1e-6f);
    }
    __syncthreads();

    f32x4 acc[4][4];
    #pragma unroll
    for (int i = 0; i < 4; i++)
        #pragma unroll
        for (int j = 0; j < 4; j++) acc[i][j] = (f32x4){0.f, 0.f, 0.f, 0.f};
    #pragma unroll
    for (int ko = 0; ko < 64; ko += 32) {
        bf16x8 af[4], bfr[4];
        #pragma unroll
        for (int f = 0; f < 4; f++)
            af[f] = *(const bf16x8*)&sQ[wave][(f * 16 + l16) * 72 + ko + quad * 8];
        #pragma unroll
        for (int f = 0; f < 4; f++)
            bfr[f] = *(const bf16x8*)&sKV[(f * 16 + l16) * 72 + ko + quad * 8];
        #pragma unroll
        for (int i = 0; i < 4; i++)
            #pragma unroll
            for (int j = 0; j < 4; j++)
                acc[i][j] = __builtin_amdgcn_mfma_f32_16x16x32_bf16(af[i], bfr[j], acc[i][j], 0, 0, 0);
    }
    size_t obase = (size_t)(b * 4096 + lbase + wave * 64);
    #pragma unroll
    for (int i = 0; i < 4; i++)
        #pragma unroll
        for (int j = 0; j < 4; j++)
            #pragma unroll
            for (int r = 0; r < 4; r++) {
                int row = i * 16 + quad * 4 + r;
                float v = acc[i][j][r] * sZ[wave * 64 + row];
                o1[(obase + row) * 512 + h * 64 + j * 16 + l16] = f2b(v);
            }
}

// ---------------- launch -----------------------------------------------------
extern "C" void kernel_launch(void* const* d_in, const int* in_sizes, int n_in,
                              void* d_out, int out_size, void* d_ws, size_t ws_size,
                              hipStream_t stream) {
    const float* x  = (const float*)d_in[0];
    const float* Wq = (const float*)d_in[1];
    const float* bq = (const float*)d_in[2];
    const float* Wk = (const float*)d_in[3];
    const float* bk = (const float*)d_in[4];
    const float* Wv = (const float*)d_in[5];
    const float* bv = (const float*)d_in[6];
    const float* Wo = (const float*)d_in[7];
    const float* bo = (const float*)d_in[8];
    float* out = (float*)d_out;

    char* ws = (char*)d_ws;
    unsigned short* xb  = (unsigned short*)(ws);                  // 32 MB, reused as o1b
    unsigned short* vb  = (unsigned short*)(ws + 33554432ull);    // 32 MB
    unsigned short* wt  = (unsigned short*)(ws + 67108864ull);    // 2 MB: Wq,Wk,Wv,Wo transposed
    float*          kvp = (float*)(ws + 69206016ull);             // 8 MB partials
    float*          ksp = (float*)(ws + 77594624ull);             // 128 KB partials
    // d_out (64 MB fp32) doubles as scratch for q,k (dead before final GEMM)
    unsigned short* qb  = (unsigned short*)d_out;                 // 32 MB
    unsigned short* kb  = (unsigned short*)((char*)d_out + 33554432ull);
    unsigned short* o1b = xb;

    cvt_f32_bf16<<<16384, 256, 0, stream>>>(x, xb, 4194304);
    transpose_w<<<dim3(8, 8, 4), 256, 0, stream>>>(Wq, Wk, Wv, Wo, wt);
    gemm_qkv_kernel<<<dim3(256, 12), 256, 0, stream>>>(xb, wt, bq, bk, bv, qb, kb, vb);
    kv_kernel<<<dim3(64, 8), 256, 0, stream>>>(kb, vb, kvp, ksp);
    out1_kernel<<<dim3(16, 64), 256, 0, stream>>>(qb, kvp, ksp, o1b);
    gemm_out_kernel<<<dim3(256, 4), 256, 0, stream>>>(o1b, wt + 3ull * 512 * 512, bo, out);
}

// Round 3
// 297.063 us; speedup vs baseline: 1.2476x; 1.1434x over previous
//
#include <hip/hip_runtime.h>
#include <hip/hip_bf16.h>

// B=8, S=4096, E=512, QKV=512, H=8, D=64, M=B*S=32768
// Pipeline:
//   cvt:       x fp32 -> bf16 (ws)
//   trans:     Wq,Wk,Wv,Wo fp32 [K][N] -> bf16 [N][K] (ws)
//   gemm_qkv:  q,k,v = act(x@W+b), bf16; q,k staged in d_out region, v in ws
//   kv:        kv[bh][m][d], ksum[bh][d] partials per s-chunk (fp32, ws)
//   reduce_kv: sum 8 partials -> kvb bf16 [bh][m*64+d], ksum fp32 [bh][64]
//   out1:      out1 = z * (q @ kv^T), bf16 (reuses x's ws region)
//   gemm_out:  out = out1 @ Wo + bo, fp32 -> d_out
//
// R3: (a) runtime act flag -> single gemm128 instantiation -> 32KB LDS/block
//     (fixes R2's 64KB dup -> 2 blocks/CU); (b) grid transposed so the 12
//     (tensor,ntile) blocks sharing one A-tile are consecutive -> L2 reuse;
//     (c) kv partials pre-reduced once instead of per-out1-block.

typedef __bf16 bf16x8 __attribute__((ext_vector_type(8)));
typedef float  f32x4  __attribute__((ext_vector_type(4)));

__device__ __forceinline__ float b2f(unsigned short u) {
    unsigned int x = ((unsigned int)u) << 16;
    return __builtin_bit_cast(float, x);
}
__device__ __forceinline__ unsigned short f2b(float f) {
    unsigned int u = __builtin_bit_cast(unsigned int, f);
    unsigned int r = (u + 0x7FFFu + ((u >> 16) & 1u)) >> 16;
    return (unsigned short)r;
}

__device__ __forceinline__ void load_lds16(const unsigned short* g, unsigned short* l) {
    __builtin_amdgcn_global_load_lds(
        (const __attribute__((address_space(1))) void*)g,
        (__attribute__((address_space(3))) void*)l, 16, 0, 0);
}

// ---------------- convert fp32 -> bf16 (vectorized, 4 elems/thread) ----------
__global__ void cvt_f32_bf16(const float* __restrict__ in,
                             unsigned short* __restrict__ out, int n4) {
    int i = blockIdx.x * blockDim.x + threadIdx.x;
    if (i >= n4) return;
    float4 v = ((const float4*)in)[i];
    ushort4 o;
    o.x = f2b(v.x); o.y = f2b(v.y); o.z = f2b(v.z); o.w = f2b(v.w);
    ((ushort4*)out)[i] = o;
}

// ---------------- transpose W [512][512] fp32 -> Wt [N][K] bf16 --------------
__global__ void transpose_w(const float* __restrict__ w0, const float* __restrict__ w1,
                            const float* __restrict__ w2, const float* __restrict__ w3,
                            unsigned short* __restrict__ wt) {
    const float* src = (blockIdx.z == 0) ? w0 : (blockIdx.z == 1) ? w1
                     : (blockIdx.z == 2) ? w2 : w3;
    unsigned short* dst = wt + (size_t)blockIdx.z * 512 * 512;
    __shared__ float tile[64][65];
    int t = threadIdx.x;
    int rb = blockIdx.y * 64, cb = blockIdx.x * 64;
    #pragma unroll
    for (int i = 0; i < 16; i++) {
        int c = t + i * 256; int r = c >> 6, cc = c & 63;
        tile[r][cc] = src[(rb + r) * 512 + cb + cc];
    }
    __syncthreads();
    #pragma unroll
    for (int i = 0; i < 16; i++) {
        int c = t + i * 256; int r = c >> 6, cc = c & 63;
        // Wt[n][k] = W[k][n]; n = cb+r, k = rb+cc
        dst[(cb + r) * 512 + rb + cc] = f2b(tile[cc][r]);
    }
}

// ---------------- 128x128 bf16 MFMA GEMM core (m97-style) --------------------
// A: [M][512] bf16 row-major. Bt: [N][512] bf16 (B pre-transposed).
// C[m][n] = sum_k A[m][k]*Bt[n][k] + bias[n], optional elu+1, out bf16 or fp32.
// LDS tiles 128x64 bf16 unpadded; 16B groups XOR-swizzled: LDS phys group p at
// row r holds logical group p^(r&7). Staged via global_load_lds (wave-uniform
// LDS base + lane*16), so the swizzle lives in each lane's global address.
// `act` is a RUNTIME wave-uniform flag (template bool caused 2 inlined copies
// with duplicated static LDS -> 64KB/block -> occupancy collapse in R2).
template <bool OUTBF>
__device__ __forceinline__ void gemm128(const unsigned short* __restrict__ A,
                                        const unsigned short* __restrict__ Bt,
                                        const float* __restrict__ bias,
                                        void* __restrict__ Cout,
                                        int mtile, int ntile, bool act) {
    __shared__ __align__(16) unsigned short sA[128 * 64];
    __shared__ __align__(16) unsigned short sB[128 * 64];
    const int tid  = threadIdx.x;
    const int wave = tid >> 6, lane = tid & 63;
    const int wm = wave >> 1, wn = wave & 1;
    const int quad = lane >> 4, l16 = lane & 15;
    const int mbase = mtile * 128, nbase = ntile * 128;
    // staging lane constants: lane covers (row r0+rsub, phys group lane&7),
    // which must hold logical col group (lane&7)^(rsub) since (r&7)==rsub.
    const int rsub = lane >> 3;
    const int coff = (((lane & 7) ^ rsub) << 3);   // element offset within row

    f32x4 acc[4][4];
    #pragma unroll
    for (int i = 0; i < 4; i++)
        #pragma unroll
        for (int j = 0; j < 4; j++) acc[i][j] = (f32x4){0.f, 0.f, 0.f, 0.f};

    for (int kb = 0; kb < 512; kb += 64) {
        #pragma unroll
        for (int t = 0; t < 4; t++) {
            int r0 = t * 32 + wave * 8;            // wave-uniform row base
            load_lds16(&A[(size_t)(mbase + r0 + rsub) * 512 + kb + coff], &sA[r0 * 64]);
            load_lds16(&Bt[(size_t)(nbase + r0 + rsub) * 512 + kb + coff], &sB[r0 * 64]);
        }
        __syncthreads();
        #pragma unroll
        for (int ko = 0; ko < 64; ko += 32) {
            bf16x8 af[4], bfr[4];
            int pg = ((quad + (ko >> 3)) ^ (l16 & 7)) << 3;  // phys group offset (elems)
            #pragma unroll
            for (int f = 0; f < 4; f++)
                af[f] = *(const bf16x8*)&sA[(wm * 64 + f * 16 + l16) * 64 + pg];
            #pragma unroll
            for (int f = 0; f < 4; f++)
                bfr[f] = *(const bf16x8*)&sB[(wn * 64 + f * 16 + l16) * 64 + pg];
            #pragma unroll
            for (int i = 0; i < 4; i++)
                #pragma unroll
                for (int j = 0; j < 4; j++)
                    acc[i][j] = __builtin_amdgcn_mfma_f32_16x16x32_bf16(af[i], bfr[j], acc[i][j], 0, 0, 0);
        }
        __syncthreads();
    }
    // epilogue: C/D layout col=lane&15, row=quad*4+reg (m89-verified)
    #pragma unroll
    for (int i = 0; i < 4; i++) {
        #pragma unroll
        for (int j = 0; j < 4; j++) {
            int gcol = nbase + wn * 64 + j * 16 + l16;
            float bv = bias[gcol];
            #pragma unroll
            for (int r = 0; r < 4; r++) {
                int grow = mbase + wm * 64 + i * 16 + quad * 4 + r;
                float v = acc[i][j][r] + bv;
                if (act) v = v > 0.f ? v + 1.f : __expf(v);
                if (OUTBF) ((unsigned short*)Cout)[(size_t)grow * 512 + gcol] = f2b(v);
                else       ((float*)Cout)[(size_t)grow * 512 + gcol] = v;
            }
        }
    }
}

// grid: x = tensor*4+ntile (12, FAST dim so consecutive blocks share A-tile),
//       y = mtile (256)
__global__ __launch_bounds__(256, 4) void gemm_qkv_kernel(
        const unsigned short* __restrict__ xb, const unsigned short* __restrict__ wt,
        const float* __restrict__ bq, const float* __restrict__ bk, const float* __restrict__ bv,
        unsigned short* __restrict__ qb, unsigned short* __restrict__ kb,
        unsigned short* __restrict__ vb) {
    int tensor = blockIdx.x >> 2, ntile = blockIdx.x & 3;
    const unsigned short* Bt = wt + (size_t)tensor * 512 * 512;
    const float* bias = tensor == 0 ? bq : tensor == 1 ? bk : bv;
    unsigned short* out = tensor == 0 ? qb : tensor == 1 ? kb : vb;
    gemm128<true>(xb, Bt, bias, out, blockIdx.y, ntile, tensor < 2);
}

// grid: x = ntile (4, fast), y = mtile (256)
__global__ __launch_bounds__(256, 4) void gemm_out_kernel(
        const unsigned short* __restrict__ o1b, const unsigned short* __restrict__ wto,
        const float* __restrict__ bo, float* __restrict__ out) {
    gemm128<false>(o1b, wto, bo, out, blockIdx.y, blockIdx.x, false);
}

// ---------------- kv + ksum partials ----------------------------------------
// grid: x = bh (64), y = sc (8).  Each block: 512 s-rows, 8x8 cells/thread,
// 4 waves split s; LDS wave-reduction; one partial buffer write, no atomics.
__global__ __launch_bounds__(256) void kv_kernel(
        const unsigned short* __restrict__ kb, const unsigned short* __restrict__ vb,
        float* __restrict__ kvp, float* __restrict__ ksp) {
    int bh = blockIdx.x, sc = blockIdx.y;
    int b = bh >> 3, h = bh & 7;
    const int tid = threadIdx.x;
    int wave = tid >> 6;
    int cell = tid & 63;
    int m0 = (cell >> 3) * 8, d0 = (cell & 7) * 8;
    __shared__ __align__(16) unsigned short sK[32 * 64];
    __shared__ __align__(16) unsigned short sV[32 * 64];
    __shared__ float sAcc[4096];
    __shared__ float sKs[64];
    float acc[8][8];
    #pragma unroll
    for (int i = 0; i < 8; i++)
        #pragma unroll
        for (int j = 0; j < 8; j++) acc[i][j] = 0.f;
    float ks = 0.f;
    size_t gbase = ((size_t)(b * 4096 + sc * 512)) * 512 + h * 64;

    for (int tile = 0; tile < 16; tile++) {
        {
            int r = tid >> 3, cc = (tid & 7) * 8;
            size_t g = gbase + (size_t)(tile * 32 + r) * 512 + cc;
            *(uint4*)&sK[r * 64 + cc] = *(const uint4*)&kb[g];
            *(uint4*)&sV[r * 64 + cc] = *(const uint4*)&vb[g];
        }
        __syncthreads();
        #pragma unroll
        for (int ss = 0; ss < 8; ss++) {
            int s = wave * 8 + ss;
            uint4 kr = *(const uint4*)&sK[s * 64 + d0];
            uint4 vr = *(const uint4*)&sV[s * 64 + m0];
            float kvals[8], vvals[8];
            const unsigned int* kp = (const unsigned int*)&kr;
            const unsigned int* vp = (const unsigned int*)&vr;
            #pragma unroll
            for (int i = 0; i < 4; i++) {
                kvals[2*i]   = __builtin_bit_cast(float, kp[i] << 16);
                kvals[2*i+1] = __builtin_bit_cast(float, kp[i] & 0xFFFF0000u);
                vvals[2*i]   = __builtin_bit_cast(float, vp[i] << 16);
                vvals[2*i+1] = __builtin_bit_cast(float, vp[i] & 0xFFFF0000u);
            }
            #pragma unroll
            for (int i = 0; i < 8; i++)
                #pragma unroll
                for (int j = 0; j < 8; j++)
                    acc[i][j] += vvals[i] * kvals[j];
            ks += b2f(sK[s * 64 + cell]);
        }
        __syncthreads();
    }
    // reduce 4 waves in LDS
    for (int w = 0; w < 4; w++) {
        if (wave == w) {
            #pragma unroll
            for (int i = 0; i < 8; i++)
                #pragma unroll
                for (int j = 0; j < 8; j++) {
                    int idx = (m0 + i) * 64 + d0 + j;
                    if (w == 0) sAcc[idx] = acc[i][j];
                    else        sAcc[idx] += acc[i][j];
                }
            if (w == 0) sKs[cell] = ks;
            else        sKs[cell] += ks;
        }
        __syncthreads();
    }
    float* kvout = kvp + ((size_t)sc * 64 + bh) * 4096;
    #pragma unroll
    for (int i = 0; i < 16; i++) {
        int idx = tid + i * 256;
        kvout[idx] = sAcc[idx];
    }
    if (tid < 64) ksp[((size_t)sc * 64 + bh) * 64 + tid] = sKs[tid];
}

// ---------------- reduce kv partials -> bf16 kvb + fp32 ksum -----------------
// grid: 64 blocks (bh) x 256 threads.
__global__ __launch_bounds__(256) void reduce_kv_kernel(
        const float* __restrict__ kvp, const float* __restrict__ ksp,
        unsigned short* __restrict__ kvb, float* __restrict__ ksum) {
    int bh = blockIdx.x, tid = threadIdx.x;
    #pragma unroll
    for (int i = 0; i < 16; i++) {
        int idx = tid + i * 256;
        float s = 0.f;
        #pragma unroll
        for (int sc = 0; sc < 8; sc++) s += kvp[((size_t)sc * 64 + bh) * 4096 + idx];
        kvb[(size_t)bh * 4096 + idx] = f2b(s);
    }
    if (tid < 64) {
        float s = 0.f;
        #pragma unroll
        for (int sc = 0; sc < 8; sc++) s += ksp[((size_t)sc * 64 + bh) * 64 + tid];
        ksum[bh * 64 + tid] = s;
    }
}

// ---------------- out1 = z * (q @ kv^T) -------------------------------------
// grid: x = lchunk (16, 256 rows each), y = bh (64). 4 waves x 64 rows.
__global__ __launch_bounds__(256) void out1_kernel(
        const unsigned short* __restrict__ qb,
        const unsigned short* __restrict__ kvb, const float* __restrict__ ksum,
        unsigned short* __restrict__ o1) {
    int bh = blockIdx.y, b = bh >> 3, h = bh & 7;
    int lbase = blockIdx.x * 256;
    int tid = threadIdx.x, wave = tid >> 6, lane = tid & 63;
    int quad = lane >> 4, l16 = lane & 15;
    __shared__ __align__(16) unsigned short sKV[64 * 72];
    __shared__ __align__(16) unsigned short sQ[4][64 * 72];
    __shared__ float sKsum[64];
    __shared__ float sZ[256];

    // stage kv (already reduced, bf16): layout [m][d] == Bt[n][k]
    #pragma unroll
    for (int i = 0; i < 2; i++) {
        int idx = (tid + i * 256) * 8;
        uint4 w = *(const uint4*)&kvb[(size_t)bh * 4096 + idx];
        *(uint4*)&sKV[(idx >> 6) * 72 + (idx & 63)] = w;
    }
    if (tid < 64) sKsum[tid] = ksum[bh * 64 + tid];
    // stage q rows for this wave
    {
        size_t qbase = ((size_t)(b * 4096 + lbase + wave * 64)) * 512 + h * 64;
        #pragma unroll
        for (int i = 0; i < 8; i++) {
            int c = lane + i * 64;
            int r = c >> 3, cc = (c & 7) * 8;
            *(uint4*)&sQ[wave][r * 72 + cc] = *(const uint4*)&qb[qbase + (size_t)r * 512 + cc];
        }
    }
    __syncthreads();
    // z per row: lane handles row=lane of its wave
    {
        float denom = 0.f;
        #pragma unroll
        for (int d = 0; d < 64; d++) denom += b2f(sQ[wave][lane * 72 + d]) * sKsum[d];
        sZ[wave * 64 + lane] = 1.f / (denom + 1e-6f);
    }
    __syncthreads();

    f32x4 acc[4][4];
    #pragma unroll
    for (int i = 0; i < 4; i++)
        #pragma unroll
        for (int j = 0; j < 4; j++) acc[i][j] = (f32x4){0.f, 0.f, 0.f, 0.f};
    #pragma unroll
    for (int ko = 0; ko < 64; ko += 32) {
        bf16x8 af[4], bfr[4];
        #pragma unroll
        for (int f = 0; f < 4; f++)
            af[f] = *(const bf16x8*)&sQ[wave][(f * 16 + l16) * 72 + ko + quad * 8];
        #pragma unroll
        for (int f = 0; f < 4; f++)
            bfr[f] = *(const bf16x8*)&sKV[(f * 16 + l16) * 72 + ko + quad * 8];
        #pragma unroll
        for (int i = 0; i < 4; i++)
            #pragma unroll
            for (int j = 0; j < 4; j++)
                acc[i][j] = __builtin_amdgcn_mfma_f32_16x16x32_bf16(af[i], bfr[j], acc[i][j], 0, 0, 0);
    }
    size_t obase = (size_t)(b * 4096 + lbase + wave * 64);
    #pragma unroll
    for (int i = 0; i < 4; i++)
        #pragma unroll
        for (int j = 0; j < 4; j++)
            #pragma unroll
            for (int r = 0; r < 4; r++) {
                int row = i * 16 + quad * 4 + r;
                float v = acc[i][j][r] * sZ[wave * 64 + row];
                o1[(obase + row) * 512 + h * 64 + j * 16 + l16] = f2b(v);
            }
}

// ---------------- launch -----------------------------------------------------
extern "C" void kernel_launch(void* const* d_in, const int* in_sizes, int n_in,
                              void* d_out, int out_size, void* d_ws, size_t ws_size,
                              hipStream_t stream) {
    const float* x  = (const float*)d_in[0];
    const float* Wq = (const float*)d_in[1];
    const float* bq = (const float*)d_in[2];
    const float* Wk = (const float*)d_in[3];
    const float* bk = (const float*)d_in[4];
    const float* Wv = (const float*)d_in[5];
    const float* bv = (const float*)d_in[6];
    const float* Wo = (const float*)d_in[7];
    const float* bo = (const float*)d_in[8];
    float* out = (float*)d_out;

    char* ws = (char*)d_ws;
    unsigned short* xb  = (unsigned short*)(ws);                  // 32 MB, reused as o1b
    unsigned short* vb  = (unsigned short*)(ws + 33554432ull);    // 32 MB; head reused for kvb/ksum
    unsigned short* wt  = (unsigned short*)(ws + 67108864ull);    // 2 MB: Wq,Wk,Wv,Wo transposed
    float*          kvp = (float*)(ws + 69206016ull);             // 8 MB partials
    float*          ksp = (float*)(ws + 77594624ull);             // 128 KB partials
    // d_out (64 MB fp32) doubles as scratch for q,k (dead before final GEMM)
    unsigned short* qb  = (unsigned short*)d_out;                 // 32 MB
    unsigned short* kb  = (unsigned short*)((char*)d_out + 33554432ull);
    unsigned short* o1b = xb;
    // kvb/ksum overwrite vb region (vb dead after kv_kernel)
    unsigned short* kvb  = vb;                                    // 512 KB
    float*          ksum = (float*)(ws + 33554432ull + 1048576ull); // 16 KB

    cvt_f32_bf16<<<16384, 256, 0, stream>>>(x, xb, 4194304);
    transpose_w<<<dim3(8, 8, 4), 256, 0, stream>>>(Wq, Wk, Wv, Wo, wt);
    gemm_qkv_kernel<<<dim3(12, 256), 256, 0, stream>>>(xb, wt, bq, bk, bv, qb, kb, vb);
    kv_kernel<<<dim3(64, 8), 256, 0, stream>>>(kb, vb, kvp, ksp);
    reduce_kv_kernel<<<64, 256, 0, stream>>>(kvp, ksp, kvb, ksum);
    out1_kernel<<<dim3(16, 64), 256, 0, stream>>>(qb, kvb, ksum, o1b);
    gemm_out_kernel<<<dim3(4, 256), 256, 0, stream>>>(o1b, wt + 3ull * 512 * 512, bo, out);
}

// Round 4
// 288.089 us; speedup vs baseline: 1.2865x; 1.0311x over previous
//
#include <hip/hip_runtime.h>
#include <hip/hip_bf16.h>

// B=8, S=4096, E=512, QKV=512, H=8, D=64, M=B*S=32768
// R4 pipeline (5 launches):
//   prep:      x fp32 -> bf16 (d_out hi half) + W transposes -> wt (ws)
//   gemm_qkv:  q,k (ws), v (d_out lo half) = act(x@W+b), bf16
//   kv:        kv/ksum partials per 256-s chunk (fp32; kvp overlays dead xb)
//   mid:       reduce ksum; z[h][row]=1/(q_h.ksum_h+eps); reduce kv -> bf16
//   fused_out: per 128x128 out block: loop h { o1_h = z*(q_h@kv_h^T) in LDS,
//              accumulate o1_h @ Wo_h } + bias -> d_out fp32
// Scratch choreography (all sequential on one stream):
//   d_out[0,32M):  vb (dead after kv), then final out rows
//   d_out[32,64M): xb (dead after gemm_qkv) -> kvp partials -> final out rows
//   ws: qb[0,32M) kb[32,64M) wt[64,66M) ksp/kvb/zb[66,68M)   (~68 MB < prior 78)

typedef __bf16 bf16x8 __attribute__((ext_vector_type(8)));
typedef float  f32x4  __attribute__((ext_vector_type(4)));

__device__ __forceinline__ float b2f(unsigned short u) {
    unsigned int x = ((unsigned int)u) << 16;
    return __builtin_bit_cast(float, x);
}
__device__ __forceinline__ unsigned short f2b(float f) {
    unsigned int u = __builtin_bit_cast(unsigned int, f);
    unsigned int r = (u + 0x7FFFu + ((u >> 16) & 1u)) >> 16;
    return (unsigned short)r;
}
__device__ __forceinline__ void load_lds16(const unsigned short* g, unsigned short* l) {
    __builtin_amdgcn_global_load_lds(
        (const __attribute__((address_space(1))) void*)g,
        (__attribute__((address_space(3))) void*)l, 16, 0, 0);
}

// ---------------- prep: W transpose (blocks 0..255) + x cvt (blocks 256..) ---
__global__ void prep_kernel(const float* __restrict__ x,
                            const float* __restrict__ w0, const float* __restrict__ w1,
                            const float* __restrict__ w2, const float* __restrict__ w3,
                            unsigned short* __restrict__ xb, unsigned short* __restrict__ wt) {
    __shared__ float tile[64][65];
    int t = threadIdx.x;
    if (blockIdx.x >= 256) {
        int i = (blockIdx.x - 256) * 256 + t;   // < 4194304
        float4 v = ((const float4*)x)[i];
        ushort4 o;
        o.x = f2b(v.x); o.y = f2b(v.y); o.z = f2b(v.z); o.w = f2b(v.w);
        ((ushort4*)xb)[i] = o;
        return;
    }
    int idx = blockIdx.x;
    int bz = idx >> 6, by = (idx >> 3) & 7, bx = idx & 7;
    const float* src = (bz == 0) ? w0 : (bz == 1) ? w1 : (bz == 2) ? w2 : w3;
    unsigned short* dst = wt + (size_t)bz * 512 * 512;
    int rb = by * 64, cb = bx * 64;
    #pragma unroll
    for (int i = 0; i < 16; i++) {
        int c = t + i * 256; int r = c >> 6, cc = c & 63;
        tile[r][cc] = src[(rb + r) * 512 + cb + cc];
    }
    __syncthreads();
    #pragma unroll
    for (int i = 0; i < 16; i++) {
        int c = t + i * 256; int r = c >> 6, cc = c & 63;
        dst[(cb + r) * 512 + rb + cc] = f2b(tile[cc][r]);   // Wt[n][k]=W[k][n]
    }
}

// ---------------- 128x128 bf16 MFMA GEMM core (m97-style, XOR-swizzled) ------
__device__ __forceinline__ void gemm128(const unsigned short* __restrict__ A,
                                        const unsigned short* __restrict__ Bt,
                                        const float* __restrict__ bias,
                                        unsigned short* __restrict__ Cout,
                                        int mtile, int ntile, bool act) {
    __shared__ __align__(16) unsigned short sA[128 * 64];
    __shared__ __align__(16) unsigned short sB[128 * 64];
    const int tid  = threadIdx.x;
    const int wave = tid >> 6, lane = tid & 63;
    const int wm = wave >> 1, wn = wave & 1;
    const int quad = lane >> 4, l16 = lane & 15;
    const int mbase = mtile * 128, nbase = ntile * 128;
    const int rsub = lane >> 3;
    const int coff = (((lane & 7) ^ rsub) << 3);

    f32x4 acc[4][4];
    #pragma unroll
    for (int i = 0; i < 4; i++)
        #pragma unroll
        for (int j = 0; j < 4; j++) acc[i][j] = (f32x4){0.f, 0.f, 0.f, 0.f};

    for (int kb = 0; kb < 512; kb += 64) {
        #pragma unroll
        for (int t = 0; t < 4; t++) {
            int r0 = t * 32 + wave * 8;
            load_lds16(&A[(size_t)(mbase + r0 + rsub) * 512 + kb + coff], &sA[r0 * 64]);
            load_lds16(&Bt[(size_t)(nbase + r0 + rsub) * 512 + kb + coff], &sB[r0 * 64]);
        }
        __syncthreads();
        #pragma unroll
        for (int ko = 0; ko < 64; ko += 32) {
            bf16x8 af[4], bfr[4];
            int pg = ((quad + (ko >> 3)) ^ (l16 & 7)) << 3;
            #pragma unroll
            for (int f = 0; f < 4; f++)
                af[f] = *(const bf16x8*)&sA[(wm * 64 + f * 16 + l16) * 64 + pg];
            #pragma unroll
            for (int f = 0; f < 4; f++)
                bfr[f] = *(const bf16x8*)&sB[(wn * 64 + f * 16 + l16) * 64 + pg];
            #pragma unroll
            for (int i = 0; i < 4; i++)
                #pragma unroll
                for (int j = 0; j < 4; j++)
                    acc[i][j] = __builtin_amdgcn_mfma_f32_16x16x32_bf16(af[i], bfr[j], acc[i][j], 0, 0, 0);
        }
        __syncthreads();
    }
    #pragma unroll
    for (int i = 0; i < 4; i++) {
        #pragma unroll
        for (int j = 0; j < 4; j++) {
            int gcol = nbase + wn * 64 + j * 16 + l16;
            float bv = bias[gcol];
            #pragma unroll
            for (int r = 0; r < 4; r++) {
                int grow = mbase + wm * 64 + i * 16 + quad * 4 + r;
                float v = acc[i][j][r] + bv;
                if (act) v = v > 0.f ? v + 1.f : __expf(v);
                Cout[(size_t)grow * 512 + gcol] = f2b(v);
            }
        }
    }
}

// grid: x = tensor*4+ntile (12, fast -> A-tile L2 reuse), y = mtile (256)
__global__ __launch_bounds__(256, 4) void gemm_qkv_kernel(
        const unsigned short* __restrict__ xb, const unsigned short* __restrict__ wt,
        const float* __restrict__ bq, const float* __restrict__ bk, const float* __restrict__ bv,
        unsigned short* __restrict__ qb, unsigned short* __restrict__ kb,
        unsigned short* __restrict__ vb) {
    int tensor = blockIdx.x >> 2, ntile = blockIdx.x & 3;
    const unsigned short* Bt = wt + (size_t)tensor * 512 * 512;
    const float* bias = tensor == 0 ? bq : tensor == 1 ? bk : bv;
    unsigned short* out = tensor == 0 ? qb : tensor == 1 ? kb : vb;
    gemm128(xb, Bt, bias, out, blockIdx.y, ntile, tensor < 2);
}

// ---------------- kv + ksum partials -----------------------------------------
// grid: x = bh (64), y = sc (16); 256 s-rows/block, 8x8 cells/thread.
__global__ __launch_bounds__(256) void kv_kernel(
        const unsigned short* __restrict__ kb, const unsigned short* __restrict__ vb,
        float* __restrict__ kvp, float* __restrict__ ksp) {
    int bh = blockIdx.x, sc = blockIdx.y;
    int b = bh >> 3, h = bh & 7;
    const int tid = threadIdx.x;
    int wave = tid >> 6;
    int cell = tid & 63;
    int m0 = (cell >> 3) * 8, d0 = (cell & 7) * 8;
    __shared__ __align__(16) unsigned short sK[32 * 64];
    __shared__ __align__(16) unsigned short sV[32 * 64];
    __shared__ float sAcc[4096];
    __shared__ float sKs[64];
    float acc[8][8];
    #pragma unroll
    for (int i = 0; i < 8; i++)
        #pragma unroll
        for (int j = 0; j < 8; j++) acc[i][j] = 0.f;
    float ks = 0.f;
    size_t gbase = ((size_t)(b * 4096 + sc * 256)) * 512 + h * 64;

    for (int tile = 0; tile < 8; tile++) {
        {
            int r = tid >> 3, cc = (tid & 7) * 8;
            size_t g = gbase + (size_t)(tile * 32 + r) * 512 + cc;
            *(uint4*)&sK[r * 64 + cc] = *(const uint4*)&kb[g];
            *(uint4*)&sV[r * 64 + cc] = *(const uint4*)&vb[g];
        }
        __syncthreads();
        #pragma unroll
        for (int ss = 0; ss < 8; ss++) {
            int s = wave * 8 + ss;
            uint4 kr = *(const uint4*)&sK[s * 64 + d0];
            uint4 vr = *(const uint4*)&sV[s * 64 + m0];
            float kvals[8], vvals[8];
            const unsigned int* kp = (const unsigned int*)&kr;
            const unsigned int* vp = (const unsigned int*)&vr;
            #pragma unroll
            for (int i = 0; i < 4; i++) {
                kvals[2*i]   = __builtin_bit_cast(float, kp[i] << 16);
                kvals[2*i+1] = __builtin_bit_cast(float, kp[i] & 0xFFFF0000u);
                vvals[2*i]   = __builtin_bit_cast(float, vp[i] << 16);
                vvals[2*i+1] = __builtin_bit_cast(float, vp[i] & 0xFFFF0000u);
            }
            #pragma unroll
            for (int i = 0; i < 8; i++)
                #pragma unroll
                for (int j = 0; j < 8; j++)
                    acc[i][j] += vvals[i] * kvals[j];
            ks += b2f(sK[s * 64 + cell]);
        }
        __syncthreads();
    }
    for (int w = 0; w < 4; w++) {
        if (wave == w) {
            #pragma unroll
            for (int i = 0; i < 8; i++)
                #pragma unroll
                for (int j = 0; j < 8; j++) {
                    int idx = (m0 + i) * 64 + d0 + j;
                    if (w == 0) sAcc[idx] = acc[i][j];
                    else        sAcc[idx] += acc[i][j];
                }
            if (w == 0) sKs[cell] = ks;
            else        sKs[cell] += ks;
        }
        __syncthreads();
    }
    float* kvout = kvp + ((size_t)sc * 64 + bh) * 4096;
    #pragma unroll
    for (int i = 0; i < 16; i++) {
        int idx = tid + i * 256;
        kvout[idx] = sAcc[idx];
    }
    if (tid < 64) ksp[((size_t)sc * 64 + bh) * 64 + tid] = sKs[tid];
}

// ---------------- mid: ksum reduce + z precompute + kv reduce ----------------
// grid: 512 blocks = bh(64) x chunk(8); chunk==0 blocks also reduce kv.
__global__ __launch_bounds__(256) void mid_kernel(
        const float* __restrict__ kvp, const float* __restrict__ ksp,
        const unsigned short* __restrict__ qb,
        unsigned short* __restrict__ kvb, float* __restrict__ zb) {
    int bh = blockIdx.x >> 3, chunk = blockIdx.x & 7;
    int b = bh >> 3, h = bh & 7;
    int tid = threadIdx.x;
    __shared__ float sKsum[64];
    if (tid < 64) {
        float s = 0.f;
        #pragma unroll
        for (int sc = 0; sc < 16; sc++) s += ksp[((size_t)sc * 64 + bh) * 64 + tid];
        sKsum[tid] = s;
    }
    __syncthreads();
    int seg = tid & 7, rsub = tid >> 3;     // 32 rows per pass, 8 lanes per row
    float ks8[8];
    #pragma unroll
    for (int j = 0; j < 8; j++) ks8[j] = sKsum[seg * 8 + j];
    #pragma unroll
    for (int p = 0; p < 16; p++) {
        int row = chunk * 512 + p * 32 + rsub;
        uint4 w = *(const uint4*)&qb[((size_t)(b * 4096 + row)) * 512 + h * 64 + seg * 8];
        const unsigned int* qp = (const unsigned int*)&w;
        float d = 0.f;
        #pragma unroll
        for (int i = 0; i < 4; i++) {
            d += __builtin_bit_cast(float, qp[i] << 16)        * ks8[2*i];
            d += __builtin_bit_cast(float, qp[i] & 0xFFFF0000u) * ks8[2*i+1];
        }
        d += __shfl_xor(d, 1, 64);
        d += __shfl_xor(d, 2, 64);
        d += __shfl_xor(d, 4, 64);
        if (seg == 0) zb[h * 32768 + b * 4096 + row] = 1.f / (d + 1e-6f);
    }
    if (chunk == 0) {
        #pragma unroll
        for (int i = 0; i < 4; i++) {
            int idx = (tid + i * 256) * 4;
            float s0 = 0.f, s1 = 0.f, s2 = 0.f, s3 = 0.f;
            #pragma unroll
            for (int sc = 0; sc < 16; sc++) {
                float4 v = *(const float4*)&kvp[((size_t)sc * 64 + bh) * 4096 + idx];
                s0 += v.x; s1 += v.y; s2 += v.z; s3 += v.w;
            }
            ushort4 o; o.x = f2b(s0); o.y = f2b(s1); o.z = f2b(s2); o.w = f2b(s3);
            *(ushort4*)&kvb[(size_t)bh * 4096 + idx] = o;
        }
    }
}

// ---------------- fused out1 + output GEMM -----------------------------------
// grid: x = ntile (4, fast -> q-tile L2 reuse), y = mtile (256).
// Per h: stage q/Wo/kv_h -> o1_h = z*(q_h@kv_h^T) -> LDS (swizzled A-layout)
// -> accumulate o1_h @ Wo_h^T. Epilogue: + bo, fp32 out.
__global__ __launch_bounds__(256, 2) void fused_out_kernel(
        const unsigned short* __restrict__ qb,
        const unsigned short* __restrict__ kvb, const float* __restrict__ zb,
        const unsigned short* __restrict__ wto, const float* __restrict__ bo,
        float* __restrict__ out) {
    __shared__ __align__(16) unsigned short sQ[128 * 64];
    __shared__ __align__(16) unsigned short sWo[128 * 64];
    __shared__ __align__(16) unsigned short sKV[64 * 64];
    __shared__ __align__(16) unsigned short sO1[128 * 64];
    __shared__ float sZ[128];
    const int tid  = threadIdx.x;
    const int wave = tid >> 6, lane = tid & 63;
    const int wm = wave >> 1, wn = wave & 1;
    const int quad = lane >> 4, l16 = lane & 15;
    const int mbase = blockIdx.y * 128, nbase = blockIdx.x * 128;
    const int b = blockIdx.y >> 5;
    const int rsub = lane >> 3;
    const int coff = (((lane & 7) ^ rsub) << 3);

    f32x4 accm[4][4];
    #pragma unroll
    for (int i = 0; i < 4; i++)
        #pragma unroll
        for (int j = 0; j < 4; j++) accm[i][j] = (f32x4){0.f, 0.f, 0.f, 0.f};

    for (int h = 0; h < 8; h++) {
        // ---- stage q-tile, Wo-tile, kv_h, z ----
        #pragma unroll
        for (int t = 0; t < 4; t++) {
            int r0 = t * 32 + wave * 8;
            load_lds16(&qb[(size_t)(mbase + r0 + rsub) * 512 + h * 64 + coff], &sQ[r0 * 64]);
            load_lds16(&wto[(size_t)(nbase + r0 + rsub) * 512 + h * 64 + coff], &sWo[r0 * 64]);
        }
        #pragma unroll
        for (int t = 0; t < 2; t++) {
            int r0 = t * 32 + wave * 8;
            load_lds16(&kvb[(size_t)(b * 8 + h) * 4096 + (r0 + rsub) * 64 + coff], &sKV[r0 * 64]);
        }
        if (tid < 128) sZ[tid] = zb[h * 32768 + mbase + tid];
        __syncthreads();
        // ---- o1 = q_h @ kv_h^T (C: 128 rows x 64 m-cols; wave 64x32) ----
        f32x4 acco[4][2];
        #pragma unroll
        for (int f = 0; f < 4; f++)
            #pragma unroll
            for (int j = 0; j < 2; j++) acco[f][j] = (f32x4){0.f, 0.f, 0.f, 0.f};
        #pragma unroll
        for (int ko = 0; ko < 64; ko += 32) {
            bf16x8 af[4], bfr[2];
            int pg = ((quad + (ko >> 3)) ^ (l16 & 7)) << 3;
            #pragma unroll
            for (int f = 0; f < 4; f++)
                af[f] = *(const bf16x8*)&sQ[(wm * 64 + f * 16 + l16) * 64 + pg];
            #pragma unroll
            for (int j = 0; j < 2; j++)
                bfr[j] = *(const bf16x8*)&sKV[(wn * 32 + j * 16 + l16) * 64 + pg];
            #pragma unroll
            for (int f = 0; f < 4; f++)
                #pragma unroll
                for (int j = 0; j < 2; j++)
                    acco[f][j] = __builtin_amdgcn_mfma_f32_16x16x32_bf16(af[f], bfr[j], acco[f][j], 0, 0, 0);
        }
        // ---- scale by z, write to sO1 (swizzled A-layout) ----
        #pragma unroll
        for (int f = 0; f < 4; f++)
            #pragma unroll
            for (int j = 0; j < 2; j++)
                #pragma unroll
                for (int r = 0; r < 4; r++) {
                    int row = wm * 64 + f * 16 + quad * 4 + r;
                    int col = wn * 32 + j * 16 + l16;
                    float v = acco[f][j][r] * sZ[row];
                    int g = col >> 3;
                    sO1[row * 64 + ((g ^ (row & 7)) << 3) + (col & 7)] = f2b(v);
                }
        __syncthreads();
        // ---- accumulate o1_h @ Wo_h (wave 64x64) ----
        #pragma unroll
        for (int ko = 0; ko < 64; ko += 32) {
            bf16x8 af[4], bfr[4];
            int pg = ((quad + (ko >> 3)) ^ (l16 & 7)) << 3;
            #pragma unroll
            for (int f = 0; f < 4; f++)
                af[f] = *(const bf16x8*)&sO1[(wm * 64 + f * 16 + l16) * 64 + pg];
            #pragma unroll
            for (int f = 0; f < 4; f++)
                bfr[f] = *(const bf16x8*)&sWo[(wn * 64 + f * 16 + l16) * 64 + pg];
            #pragma unroll
            for (int i = 0; i < 4; i++)
                #pragma unroll
                for (int j = 0; j < 4; j++)
                    accm[i][j] = __builtin_amdgcn_mfma_f32_16x16x32_bf16(af[i], bfr[j], accm[i][j], 0, 0, 0);
        }
        __syncthreads();   // before next-h staging overwrites sQ/sWo/sKV (and sO1)
    }
    // ---- epilogue: + bias, fp32 store ----
    #pragma unroll
    for (int i = 0; i < 4; i++)
        #pragma unroll
        for (int j = 0; j < 4; j++) {
            int gcol = nbase + wn * 64 + j * 16 + l16;
            float bv = bo[gcol];
            #pragma unroll
            for (int r = 0; r < 4; r++) {
                int grow = mbase + wm * 64 + i * 16 + quad * 4 + r;
                out[(size_t)grow * 512 + gcol] = accm[i][j][r] + bv;
            }
        }
}

// ---------------- launch -----------------------------------------------------
extern "C" void kernel_launch(void* const* d_in, const int* in_sizes, int n_in,
                              void* d_out, int out_size, void* d_ws, size_t ws_size,
                              hipStream_t stream) {
    const float* x  = (const float*)d_in[0];
    const float* Wq = (const float*)d_in[1];
    const float* bq = (const float*)d_in[2];
    const float* Wk = (const float*)d_in[3];
    const float* bk = (const float*)d_in[4];
    const float* Wv = (const float*)d_in[5];
    const float* bv = (const float*)d_in[6];
    const float* Wo = (const float*)d_in[7];
    const float* bo = (const float*)d_in[8];
    float* out = (float*)d_out;

    char* wsb = (char*)d_ws;
    char* ob  = (char*)d_out;
    // d_out scratch (dead before fused_out writes):
    unsigned short* vb  = (unsigned short*)ob;                    // 32 MB
    unsigned short* xb  = (unsigned short*)(ob + 33554432ull);    // 32 MB, dead after gemm_qkv
    float*          kvp = (float*)(ob + 33554432ull);             // 16.8 MB, overlays xb
    // ws:
    unsigned short* qb  = (unsigned short*)wsb;                   // 32 MB
    unsigned short* kb  = (unsigned short*)(wsb + 33554432ull);   // 32 MB
    unsigned short* wt  = (unsigned short*)(wsb + 67108864ull);   // 2 MB
    float*          ksp = (float*)(wsb + 69206016ull);            // 256 KB
    unsigned short* kvb = (unsigned short*)(wsb + 69468160ull);   // 512 KB
    float*          zb  = (float*)(wsb + 69992448ull);            // 1 MB

    prep_kernel<<<16640, 256, 0, stream>>>(x, Wq, Wk, Wv, Wo, xb, wt);
    gemm_qkv_kernel<<<dim3(12, 256), 256, 0, stream>>>(xb, wt, bq, bk, bv, qb, kb, vb);
    kv_kernel<<<dim3(64, 16), 256, 0, stream>>>(kb, vb, kvp, ksp);
    mid_kernel<<<512, 256, 0, stream>>>(kvp, ksp, qb, kvb, zb);
    fused_out_kernel<<<dim3(4, 256), 256, 0, stream>>>(qb, kvb, zb,
            wt + 3ull * 512 * 512, bo, out);
}

// Round 5
// 263.732 us; speedup vs baseline: 1.4053x; 1.0924x over previous
//
#include <hip/hip_runtime.h>
#include <hip/hip_bf16.h>

// B=8, S=4096, E=512, QKV=512, H=8, D=64, M=B*S=32768
// R5 pipeline (5 launches):
//   prep:      x fp32 -> bf16 (d_out hi half) + W transposes -> wt (ws)
//   gemm_qkv:  q = act(x@Wq+b) row-major (ws); k,v stored ONLY TRANSPOSED
//              kT/vT[bh][d|m][4096] bf16 (k act'd), XCD-swizzled grid
//   kv:        MFMA GEMM over s: kv_part[m][d] = sum_s vT[m][s]*kT[d][s],
//              + ksum partials from staged kT tiles (16 s-chunks)
//   mid:       reduce ksum; z[h][row]=1/(q_h.ksum_h+eps); reduce kv -> bf16
//   fused_out: per 128x128 out block: loop h { o1_h = z*(q_h@kv_h^T) in LDS,
//              accumulate o1_h @ Wo_h } + bias -> d_out fp32 (XCD-swizzled)
// Scratch:
//   d_out[0,32M):  vT (dead after kv), then final out rows
//   d_out[32,64M): xb (dead after gemm_qkv) -> kvp partials -> final out rows
//   ws: qb[0,32M) kT[32,64M) wt[64,66M) ksp/kvb/zb[66,~71M)

typedef __bf16 bf16x8 __attribute__((ext_vector_type(8)));
typedef float  f32x4  __attribute__((ext_vector_type(4)));

__device__ __forceinline__ float b2f(unsigned short u) {
    unsigned int x = ((unsigned int)u) << 16;
    return __builtin_bit_cast(float, x);
}
__device__ __forceinline__ unsigned short f2b(float f) {
    unsigned int u = __builtin_bit_cast(unsigned int, f);
    unsigned int r = (u + 0x7FFFu + ((u >> 16) & 1u)) >> 16;
    return (unsigned short)r;
}
__device__ __forceinline__ void load_lds16(const unsigned short* g, unsigned short* l) {
    __builtin_amdgcn_global_load_lds(
        (const __attribute__((address_space(1))) void*)g,
        (__attribute__((address_space(3))) void*)l, 16, 0, 0);
}

// ---------------- prep: W transpose (blocks 0..255) + x cvt (blocks 256..) ---
__global__ void prep_kernel(const float* __restrict__ x,
                            const float* __restrict__ w0, const float* __restrict__ w1,
                            const float* __restrict__ w2, const float* __restrict__ w3,
                            unsigned short* __restrict__ xb, unsigned short* __restrict__ wt) {
    __shared__ float tile[64][65];
    int t = threadIdx.x;
    if (blockIdx.x >= 256) {
        int i = (blockIdx.x - 256) * 256 + t;   // < 4194304
        float4 v = ((const float4*)x)[i];
        ushort4 o;
        o.x = f2b(v.x); o.y = f2b(v.y); o.z = f2b(v.z); o.w = f2b(v.w);
        ((ushort4*)xb)[i] = o;
        return;
    }
    int idx = blockIdx.x;
    int bz = idx >> 6, by = (idx >> 3) & 7, bx = idx & 7;
    const float* src = (bz == 0) ? w0 : (bz == 1) ? w1 : (bz == 2) ? w2 : w3;
    unsigned short* dst = wt + (size_t)bz * 512 * 512;
    int rb = by * 64, cb = bx * 64;
    #pragma unroll
    for (int i = 0; i < 16; i++) {
        int c = t + i * 256; int r = c >> 6, cc = c & 63;
        tile[r][cc] = src[(rb + r) * 512 + cb + cc];
    }
    __syncthreads();
    #pragma unroll
    for (int i = 0; i < 16; i++) {
        int c = t + i * 256; int r = c >> 6, cc = c & 63;
        dst[(cb + r) * 512 + rb + cc] = f2b(tile[cc][r]);   // Wt[n][k]=W[k][n]
    }
}

// ---------------- gemm_qkv: 128x128 MFMA, q row-major / k,v transposed -------
// grid: 3072 1-D, XCD-swizzled: all 12 (tensor,ntile) blocks of one mtile get
// equal blockIdx%8 -> same XCD -> A-tile L2 hit.
__global__ __launch_bounds__(256, 4) void gemm_qkv_kernel(
        const unsigned short* __restrict__ xb, const unsigned short* __restrict__ wt,
        const float* __restrict__ bq, const float* __restrict__ bk, const float* __restrict__ bv,
        unsigned short* __restrict__ qb, unsigned short* __restrict__ kT,
        unsigned short* __restrict__ vT) {
    int g = blockIdx.x;
    int xcd = g & 7, slot = g >> 3;            // slot 0..383
    int mtile = xcd * 32 + slot / 12;
    int tn = slot % 12;
    int tensor = tn >> 2, ntile = tn & 3;
    const unsigned short* Bt = wt + (size_t)tensor * 512 * 512;
    const float* bias = tensor == 0 ? bq : tensor == 1 ? bk : bv;
    bool act = tensor < 2;

    __shared__ __align__(16) unsigned short sA[128 * 64];
    __shared__ __align__(16) unsigned short sB[128 * 64];
    const int tid  = threadIdx.x;
    const int wave = tid >> 6, lane = tid & 63;
    const int wm = wave >> 1, wn = wave & 1;
    const int quad = lane >> 4, l16 = lane & 15;
    const int mbase = mtile * 128, nbase = ntile * 128;
    const int rsub = lane >> 3;
    const int coff = (((lane & 7) ^ rsub) << 3);

    f32x4 acc[4][4];
    #pragma unroll
    for (int i = 0; i < 4; i++)
        #pragma unroll
        for (int j = 0; j < 4; j++) acc[i][j] = (f32x4){0.f, 0.f, 0.f, 0.f};

    for (int kb = 0; kb < 512; kb += 64) {
        #pragma unroll
        for (int t = 0; t < 4; t++) {
            int r0 = t * 32 + wave * 8;
            load_lds16(&xb[(size_t)(mbase + r0 + rsub) * 512 + kb + coff], &sA[r0 * 64]);
            load_lds16(&Bt[(size_t)(nbase + r0 + rsub) * 512 + kb + coff], &sB[r0 * 64]);
        }
        __syncthreads();
        #pragma unroll
        for (int ko = 0; ko < 64; ko += 32) {
            bf16x8 af[4], bfr[4];
            int pg = ((quad + (ko >> 3)) ^ (l16 & 7)) << 3;
            #pragma unroll
            for (int f = 0; f < 4; f++)
                af[f] = *(const bf16x8*)&sA[(wm * 64 + f * 16 + l16) * 64 + pg];
            #pragma unroll
            for (int f = 0; f < 4; f++)
                bfr[f] = *(const bf16x8*)&sB[(wn * 64 + f * 16 + l16) * 64 + pg];
            #pragma unroll
            for (int i = 0; i < 4; i++)
                #pragma unroll
                for (int j = 0; j < 4; j++)
                    acc[i][j] = __builtin_amdgcn_mfma_f32_16x16x32_bf16(af[i], bfr[j], acc[i][j], 0, 0, 0);
        }
        __syncthreads();
    }
    // epilogue. C/D layout: col = lane&15, row = quad*4+reg (m89-verified).
    if (tensor == 0) {
        #pragma unroll
        for (int i = 0; i < 4; i++)
            #pragma unroll
            for (int j = 0; j < 4; j++) {
                int gcol = nbase + wn * 64 + j * 16 + l16;
                float bv = bias[gcol];
                #pragma unroll
                for (int r = 0; r < 4; r++) {
                    int grow = mbase + wm * 64 + i * 16 + quad * 4 + r;
                    float v = acc[i][j][r] + bv;
                    v = v > 0.f ? v + 1.f : __expf(v);
                    qb[(size_t)grow * 512 + gcol] = f2b(v);
                }
            }
    } else {
        // transposed store: T[((b*8+h)*64 + d)*4096 + s], 4 consecutive s
        // (the 4 acc regs = rows quad*4+0..3) packed into one ushort4.
        unsigned short* T = (tensor == 1) ? kT : vT;
        #pragma unroll
        for (int i = 0; i < 4; i++)
            #pragma unroll
            for (int j = 0; j < 4; j++) {
                int gcol = nbase + wn * 64 + j * 16 + l16;   // 0..511
                int h = gcol >> 6, d = gcol & 63;
                float bv = bias[gcol];
                int grow0 = mbase + wm * 64 + i * 16 + quad * 4;
                int b = grow0 >> 12, s0 = grow0 & 4095;
                ushort4 o;
                #pragma unroll
                for (int r = 0; r < 4; r++) {
                    float v = acc[i][j][r] + bv;
                    if (act) v = v > 0.f ? v + 1.f : __expf(v);
                    ((unsigned short*)&o)[r] = f2b(v);
                }
                *(ushort4*)&T[(((size_t)b * 8 + h) * 64 + d) * 4096 + s0] = o;
            }
    }
}

// ---------------- kv: MFMA GEMM over s + ksum --------------------------------
// grid: x = bh(64) * sc(16); block: C[64 m][64 d] partial over 256 s.
// A = vT rows (m), B = kT rows (d), both K-major -> m97 staging applies.
__global__ __launch_bounds__(256, 4) void kv_kernel(
        const unsigned short* __restrict__ kT, const unsigned short* __restrict__ vT,
        float* __restrict__ kvp, float* __restrict__ ksp) {
    int bh = blockIdx.x >> 4, sc = blockIdx.x & 15;
    const int tid = threadIdx.x;
    const int wave = tid >> 6, lane = tid & 63;
    const int wm = wave >> 1, wn = wave & 1;
    const int quad = lane >> 4, l16 = lane & 15;
    const int rsub = lane >> 3;
    const int coff = (((lane & 7) ^ rsub) << 3);
    __shared__ __align__(16) unsigned short sV[64 * 64];
    __shared__ __align__(16) unsigned short sK[64 * 64];
    __shared__ float sKs[256];

    f32x4 acc[2][2];
    #pragma unroll
    for (int i = 0; i < 2; i++)
        #pragma unroll
        for (int j = 0; j < 2; j++) acc[i][j] = (f32x4){0.f, 0.f, 0.f, 0.f};
    float ks = 0.f;
    const int dks = tid >> 2, sgks = tid & 3;
    size_t base = (size_t)bh * 64 * 4096 + sc * 256;

    for (int kb = 0; kb < 4; kb++) {           // 4 x 64 s
        int s0 = kb * 64;
        #pragma unroll
        for (int t = 0; t < 2; t++) {
            int r0 = t * 32 + wave * 8;
            load_lds16(&vT[base + (size_t)(r0 + rsub) * 4096 + s0 + coff], &sV[r0 * 64]);
            load_lds16(&kT[base + (size_t)(r0 + rsub) * 4096 + s0 + coff], &sK[r0 * 64]);
        }
        __syncthreads();
        // ksum partial: thread owns (d=tid>>2, 16 s = 2 octets); unswizzle.
        #pragma unroll
        for (int gi = 0; gi < 2; gi++) {
            int gg = sgks * 2 + gi;
            int pg = ((gg ^ (dks & 7)) << 3);
            uint4 w = *(const uint4*)&sK[dks * 64 + pg];
            const unsigned int* wp = (const unsigned int*)&w;
            #pragma unroll
            for (int i2 = 0; i2 < 4; i2++) {
                ks += __builtin_bit_cast(float, wp[i2] << 16);
                ks += __builtin_bit_cast(float, wp[i2] & 0xFFFF0000u);
            }
        }
        #pragma unroll
        for (int ko = 0; ko < 64; ko += 32) {
            bf16x8 af[2], bfr[2];
            int pg = ((quad + (ko >> 3)) ^ (l16 & 7)) << 3;
            #pragma unroll
            for (int f = 0; f < 2; f++)
                af[f] = *(const bf16x8*)&sV[(wm * 32 + f * 16 + l16) * 64 + pg];
            #pragma unroll
            for (int f = 0; f < 2; f++)
                bfr[f] = *(const bf16x8*)&sK[(wn * 32 + f * 16 + l16) * 64 + pg];
            #pragma unroll
            for (int i = 0; i < 2; i++)
                #pragma unroll
                for (int j = 0; j < 2; j++)
                    acc[i][j] = __builtin_amdgcn_mfma_f32_16x16x32_bf16(af[i], bfr[j], acc[i][j], 0, 0, 0);
        }
        __syncthreads();
    }
    // write fp32 partial: kvp[sc][bh][m*64+d]
    float* kvout = kvp + ((size_t)sc * 64 + bh) * 4096;
    #pragma unroll
    for (int i = 0; i < 2; i++)
        #pragma unroll
        for (int j = 0; j < 2; j++)
            #pragma unroll
            for (int r = 0; r < 4; r++) {
                int m = wm * 32 + i * 16 + quad * 4 + r;
                int d = wn * 32 + j * 16 + l16;
                kvout[m * 64 + d] = acc[i][j][r];
            }
    sKs[tid] = ks;
    __syncthreads();
    if (tid < 64)
        ksp[((size_t)sc * 64 + bh) * 64 + tid] =
            sKs[tid * 4] + sKs[tid * 4 + 1] + sKs[tid * 4 + 2] + sKs[tid * 4 + 3];
}

// ---------------- mid: ksum reduce + z precompute + kv reduce ----------------
// grid: 512 blocks = bh(64) x chunk(8); chunk==0 blocks also reduce kv.
__global__ __launch_bounds__(256) void mid_kernel(
        const float* __restrict__ kvp, const float* __restrict__ ksp,
        const unsigned short* __restrict__ qb,
        unsigned short* __restrict__ kvb, float* __restrict__ zb) {
    int bh = blockIdx.x >> 3, chunk = blockIdx.x & 7;
    int b = bh >> 3, h = bh & 7;
    int tid = threadIdx.x;
    __shared__ float sKsum[64];
    if (tid < 64) {
        float s = 0.f;
        #pragma unroll
        for (int sc = 0; sc < 16; sc++) s += ksp[((size_t)sc * 64 + bh) * 64 + tid];
        sKsum[tid] = s;
    }
    __syncthreads();
    int seg = tid & 7, rsub = tid >> 3;     // 32 rows per pass, 8 lanes per row
    float ks8[8];
    #pragma unroll
    for (int j = 0; j < 8; j++) ks8[j] = sKsum[seg * 8 + j];
    #pragma unroll
    for (int p = 0; p < 16; p++) {
        int row = chunk * 512 + p * 32 + rsub;
        uint4 w = *(const uint4*)&qb[((size_t)(b * 4096 + row)) * 512 + h * 64 + seg * 8];
        const unsigned int* qp = (const unsigned int*)&w;
        float d = 0.f;
        #pragma unroll
        for (int i = 0; i < 4; i++) {
            d += __builtin_bit_cast(float, qp[i] << 16)        * ks8[2*i];
            d += __builtin_bit_cast(float, qp[i] & 0xFFFF0000u) * ks8[2*i+1];
        }
        d += __shfl_xor(d, 1, 64);
        d += __shfl_xor(d, 2, 64);
        d += __shfl_xor(d, 4, 64);
        if (seg == 0) zb[h * 32768 + b * 4096 + row] = 1.f / (d + 1e-6f);
    }
    if (chunk == 0) {
        #pragma unroll
        for (int i = 0; i < 4; i++) {
            int idx = (tid + i * 256) * 4;
            float s0 = 0.f, s1 = 0.f, s2 = 0.f, s3 = 0.f;
            #pragma unroll
            for (int sc = 0; sc < 16; sc++) {
                float4 v = *(const float4*)&kvp[((size_t)sc * 64 + bh) * 4096 + idx];
                s0 += v.x; s1 += v.y; s2 += v.z; s3 += v.w;
            }
            ushort4 o; o.x = f2b(s0); o.y = f2b(s1); o.z = f2b(s2); o.w = f2b(s3);
            *(ushort4*)&kvb[(size_t)bh * 4096 + idx] = o;
        }
    }
}

// ---------------- fused out1 + output GEMM -----------------------------------
// grid: 1024 1-D, XCD-swizzled (4 ntile blocks of one mtile -> same XCD).
__global__ __launch_bounds__(256, 2) void fused_out_kernel(
        const unsigned short* __restrict__ qb,
        const unsigned short* __restrict__ kvb, const float* __restrict__ zb,
        const unsigned short* __restrict__ wto, const float* __restrict__ bo,
        float* __restrict__ out) {
    int g = blockIdx.x;
    int xcd = g & 7, slot = g >> 3;            // slot 0..127
    int mtile = xcd * 32 + (slot >> 2);
    int ntile = slot & 3;

    __shared__ __align__(16) unsigned short sQ[128 * 64];
    __shared__ __align__(16) unsigned short sWo[128 * 64];
    __shared__ __align__(16) unsigned short sKV[64 * 64];
    __shared__ __align__(16) unsigned short sO1[128 * 64];
    __shared__ float sZ[128];
    const int tid  = threadIdx.x;
    const int wave = tid >> 6, lane = tid & 63;
    const int wm = wave >> 1, wn = wave & 1;
    const int quad = lane >> 4, l16 = lane & 15;
    const int mbase = mtile * 128, nbase = ntile * 128;
    const int b = mtile >> 5;
    const int rsub = lane >> 3;
    const int coff = (((lane & 7) ^ rsub) << 3);

    f32x4 accm[4][4];
    #pragma unroll
    for (int i = 0; i < 4; i++)
        #pragma unroll
        for (int j = 0; j < 4; j++) accm[i][j] = (f32x4){0.f, 0.f, 0.f, 0.f};

    for (int h = 0; h < 8; h++) {
        #pragma unroll
        for (int t = 0; t < 4; t++) {
            int r0 = t * 32 + wave * 8;
            load_lds16(&qb[(size_t)(mbase + r0 + rsub) * 512 + h * 64 + coff], &sQ[r0 * 64]);
            load_lds16(&wto[(size_t)(nbase + r0 + rsub) * 512 + h * 64 + coff], &sWo[r0 * 64]);
        }
        #pragma unroll
        for (int t = 0; t < 2; t++) {
            int r0 = t * 32 + wave * 8;
            load_lds16(&kvb[(size_t)(b * 8 + h) * 4096 + (r0 + rsub) * 64 + coff], &sKV[r0 * 64]);
        }
        if (tid < 128) sZ[tid] = zb[h * 32768 + mbase + tid];
        __syncthreads();
        // o1 = q_h @ kv_h^T  (wave computes 64 rows x 32 m-cols)
        f32x4 acco[4][2];
        #pragma unroll
        for (int f = 0; f < 4; f++)
            #pragma unroll
            for (int j = 0; j < 2; j++) acco[f][j] = (f32x4){0.f, 0.f, 0.f, 0.f};
        #pragma unroll
        for (int ko = 0; ko < 64; ko += 32) {
            bf16x8 af[4], bfr[2];
            int pg = ((quad + (ko >> 3)) ^ (l16 & 7)) << 3;
            #pragma unroll
            for (int f = 0; f < 4; f++)
                af[f] = *(const bf16x8*)&sQ[(wm * 64 + f * 16 + l16) * 64 + pg];
            #pragma unroll
            for (int j = 0; j < 2; j++)
                bfr[j] = *(const bf16x8*)&sKV[(wn * 32 + j * 16 + l16) * 64 + pg];
            #pragma unroll
            for (int f = 0; f < 4; f++)
                #pragma unroll
                for (int j = 0; j < 2; j++)
                    acco[f][j] = __builtin_amdgcn_mfma_f32_16x16x32_bf16(af[f], bfr[j], acco[f][j], 0, 0, 0);
        }
        // scale by z, write to sO1 (swizzled A-layout)
        #pragma unroll
        for (int f = 0; f < 4; f++)
            #pragma unroll
            for (int j = 0; j < 2; j++)
                #pragma unroll
                for (int r = 0; r < 4; r++) {
                    int row = wm * 64 + f * 16 + quad * 4 + r;
                    int col = wn * 32 + j * 16 + l16;
                    float v = acco[f][j][r] * sZ[row];
                    int grp = col >> 3;
                    sO1[row * 64 + ((grp ^ (row & 7)) << 3) + (col & 7)] = f2b(v);
                }
        __syncthreads();
        // accumulate o1_h @ Wo_h
        #pragma unroll
        for (int ko = 0; ko < 64; ko += 32) {
            bf16x8 af[4], bfr[4];
            int pg = ((quad + (ko >> 3)) ^ (l16 & 7)) << 3;
            #pragma unroll
            for (int f = 0; f < 4; f++)
                af[f] = *(const bf16x8*)&sO1[(wm * 64 + f * 16 + l16) * 64 + pg];
            #pragma unroll
            for (int f = 0; f < 4; f++)
                bfr[f] = *(const bf16x8*)&sWo[(wn * 64 + f * 16 + l16) * 64 + pg];
            #pragma unroll
            for (int i = 0; i < 4; i++)
                #pragma unroll
                for (int j = 0; j < 4; j++)
                    accm[i][j] = __builtin_amdgcn_mfma_f32_16x16x32_bf16(af[i], bfr[j], accm[i][j], 0, 0, 0);
        }
        __syncthreads();
    }
    #pragma unroll
    for (int i = 0; i < 4; i++)
        #pragma unroll
        for (int j = 0; j < 4; j++) {
            int gcol = nbase + wn * 64 + j * 16 + l16;
            float bv = bo[gcol];
            #pragma unroll
            for (int r = 0; r < 4; r++) {
                int grow = mbase + wm * 64 + i * 16 + quad * 4 + r;
                out[(size_t)grow * 512 + gcol] = accm[i][j][r] + bv;
            }
        }
}

// ---------------- launch -----------------------------------------------------
extern "C" void kernel_launch(void* const* d_in, const int* in_sizes, int n_in,
                              void* d_out, int out_size, void* d_ws, size_t ws_size,
                              hipStream_t stream) {
    const float* x  = (const float*)d_in[0];
    const float* Wq = (const float*)d_in[1];
    const float* bq = (const float*)d_in[2];
    const float* Wk = (const float*)d_in[3];
    const float* bk = (const float*)d_in[4];
    const float* Wv = (const float*)d_in[5];
    const float* bv = (const float*)d_in[6];
    const float* Wo = (const float*)d_in[7];
    const float* bo = (const float*)d_in[8];
    float* out = (float*)d_out;

    char* wsb = (char*)d_ws;
    char* ob  = (char*)d_out;
    // d_out scratch (dead before fused_out writes):
    unsigned short* vT  = (unsigned short*)ob;                    // 32 MB
    unsigned short* xb  = (unsigned short*)(ob + 33554432ull);    // 32 MB, dead after gemm_qkv
    float*          kvp = (float*)(ob + 33554432ull);             // 16.8 MB, overlays xb
    // ws:
    unsigned short* qb  = (unsigned short*)wsb;                   // 32 MB
    unsigned short* kT  = (unsigned short*)(wsb + 33554432ull);   // 32 MB
    unsigned short* wt  = (unsigned short*)(wsb + 67108864ull);   // 2 MB
    float*          ksp = (float*)(wsb + 69206016ull);            // 256 KB
    unsigned short* kvb = (unsigned short*)(wsb + 69468160ull);   // 512 KB
    float*          zb  = (float*)(wsb + 69992448ull);            // 1 MB

    prep_kernel<<<16640, 256, 0, stream>>>(x, Wq, Wk, Wv, Wo, xb, wt);
    gemm_qkv_kernel<<<3072, 256, 0, stream>>>(xb, wt, bq, bk, bv, qb, kT, vT);
    kv_kernel<<<1024, 256, 0, stream>>>(kT, vT, kvp, ksp);
    mid_kernel<<<512, 256, 0, stream>>>(kvp, ksp, qb, kvb, zb);
    fused_out_kernel<<<1024, 256, 0, stream>>>(qb, kvb, zb,
            wt + 3ull * 512 * 512, bo, out);
}